// Round 4
// baseline (1097.989 us; speedup 1.0000x reference)
//
#include <hip/hip_runtime.h>

// ============================================================================
// EncoderLayer: x -> MHA(+residual,LN) -> FFN(+residual,LN)
// B=4 S=2048 H=1024 F=4096 nh=8 d=128.
// Inputs fp32; OUTPUT fp32 (reference's output dtype, per harness contract —
// round-4 experiment: rounds 2/3 wrote bf16 and saw the exact misread
// signature absmax≈sqrt(2)*max|ref|). Core compute bf16 MFMA; Q/K path split
// hi/lo bf16 (faithful scores*=sqrt(d) bug -> logit sigma ~128).
// Mechanisms still correctness-first (naive transposes, register-staged LDS);
// re-add optimized mechanisms one per round once green.
// ============================================================================

typedef __bf16 bf16;
typedef __bf16 bf16x4 __attribute__((ext_vector_type(4)));
typedef __bf16 bf16x8 __attribute__((ext_vector_type(8)));
typedef float  f32x4  __attribute__((ext_vector_type(4)));

#define MFMA16(a, b, c) __builtin_amdgcn_mfma_f32_16x16x32_bf16(a, b, c, 0, 0, 0)

// ---------------------------------------------------------------------------
// x (fp32) -> hi/lo bf16 split. One float4 per thread.
// ---------------------------------------------------------------------------
__global__ __launch_bounds__(256) void split_f32_k(
    const float* __restrict__ in, bf16* __restrict__ hi, bf16* __restrict__ lo)
{
    const long i = (long)blockIdx.x * 256 + threadIdx.x;
    const float4 v = *(const float4*)(in + i * 4);
    const float a[4] = {v.x, v.y, v.z, v.w};
    bf16x4 h, l;
#pragma unroll
    for (int j = 0; j < 4; j++) {
        h[j] = (bf16)a[j];
        l[j] = (bf16)(a[j] - (float)h[j]);
    }
    *(bf16x4*)(hi + i * 4) = h;
    *(bf16x4*)(lo + i * 4) = l;
}

// ---------------------------------------------------------------------------
// Naive fp32 [R][C] -> bf16 [C][R] transpose (hi + optional lo residual).
// ---------------------------------------------------------------------------
__global__ __launch_bounds__(256) void naive_tr_w_k(
    const float* __restrict__ in, bf16* __restrict__ out_hi,
    bf16* __restrict__ out_lo, int R, int C)
{
    const long idx = (long)blockIdx.x * 256 + threadIdx.x;
    if (idx >= (long)R * C) return;
    const int r = (int)(idx / C);
    const int c = (int)(idx % C);
    const float v = in[idx];
    const bf16 h = (bf16)v;
    out_hi[(long)c * R + r] = h;
    if (out_lo) out_lo[(long)c * R + r] = (bf16)(v - (float)h);
}

// ---------------------------------------------------------------------------
// Naive per-head V transpose: vbuf[b*2048+s][h*128+dd] -> vt[bh][dd][s].
// ---------------------------------------------------------------------------
__global__ __launch_bounds__(256) void naive_tr_v_k(
    const bf16* __restrict__ in, bf16* __restrict__ out)
{
    const int z = blockIdx.z;              // bh = b*8+h
    const int b = z >> 3, h = z & 7;
    const int idx = blockIdx.x * 256 + threadIdx.x;   // over 2048*128
    const int s = idx >> 7, dd = idx & 127;
    const bf16 v = in[(long)(b * 2048 + s) * 1024 + h * 128 + dd];
    out[(long)z * 128 * 2048 + (long)dd * 2048 + s] = v;
}

// ---------------------------------------------------------------------------
// GEMM: C[M,N] = A[M,K] @ Bt[N,K]^T  (bf16, fp32 acc). 128x128 tile, BK=32,
// register-staged LDS, 4 waves x (64x64 = 4x4 MFMA).
// ---------------------------------------------------------------------------
__global__ __launch_bounds__(256) void gemm_bf16_k(
    const bf16* __restrict__ A, const bf16* __restrict__ Bt,
    bf16* __restrict__ out,
    const float* __restrict__ bias, int relu, int M, int N, int K)
{
    __shared__ __align__(16) bf16 As[128 * 32];
    __shared__ __align__(16) bf16 Bs[128 * 32];
    const int t = threadIdx.x;
    const int fr = t & 15, fq = (t >> 4) & 3;
    const int w = t >> 6, wm = w & 1, wn = w >> 1;
    const long mBase = (long)blockIdx.y * 128;
    const long nBase = (long)blockIdx.x * 128;

    f32x4 acc[4][4];
#pragma unroll
    for (int i = 0; i < 4; i++)
#pragma unroll
        for (int j = 0; j < 4; j++) acc[i][j] = (f32x4){0.f, 0.f, 0.f, 0.f};

    const int arow = t >> 2;
    const int akc  = (t & 3) * 8;
    const bf16* ga0 = A + (mBase + arow) * (long)K + akc;
    const bf16* ga1 = A + (mBase + arow + 64) * (long)K + akc;
    const bf16* gb0 = Bt + (nBase + arow) * (long)K + akc;
    const bf16* gb1 = Bt + (nBase + arow + 64) * (long)K + akc;

    const int aoff = (wm * 64 + fr) * 32 + fq * 8;
    const int boff = (wn * 64 + fr) * 32 + fq * 8;

    for (int kt = 0; kt < K; kt += 32) {
        const bf16x8 va0 = *(const bf16x8*)(ga0 + kt);
        const bf16x8 va1 = *(const bf16x8*)(ga1 + kt);
        const bf16x8 vb0 = *(const bf16x8*)(gb0 + kt);
        const bf16x8 vb1 = *(const bf16x8*)(gb1 + kt);
        *(bf16x8*)&As[t * 8] = va0;
        *(bf16x8*)&As[(256 + t) * 8] = va1;
        *(bf16x8*)&Bs[t * 8] = vb0;
        *(bf16x8*)&Bs[(256 + t) * 8] = vb1;
        __syncthreads();
        bf16x8 af[4], bfv[4];
#pragma unroll
        for (int mt = 0; mt < 4; mt++) af[mt] = *(const bf16x8*)&As[aoff + mt * 512];
#pragma unroll
        for (int nt = 0; nt < 4; nt++) bfv[nt] = *(const bf16x8*)&Bs[boff + nt * 512];
#pragma unroll
        for (int mt = 0; mt < 4; mt++)
#pragma unroll
            for (int nt = 0; nt < 4; nt++)
                acc[mt][nt] = MFMA16(af[mt], bfv[nt], acc[mt][nt]);
        __syncthreads();
    }

    const long crow0 = mBase + wm * 64;
    const long ccol0 = nBase + wn * 64;
#pragma unroll
    for (int nt = 0; nt < 4; nt++) {
        const long col = ccol0 + nt * 16 + fr;
        const float bv = bias ? bias[col] : 0.0f;
#pragma unroll
        for (int mt = 0; mt < 4; mt++)
#pragma unroll
            for (int r = 0; r < 4; r++) {
                const long rowg = crow0 + mt * 16 + fq * 4 + r;  // C/D: col=lane&15, row=quad*4+reg
                float v = acc[mt][nt][r] + bv;
                if (relu) v = fmaxf(v, 0.0f);
                out[rowg * (long)N + col] = (bf16)v;
            }
    }
}

// ---------------------------------------------------------------------------
// Split-precision GEMM for Q/K projections:
//   C = Ah@Bh^T + Ah@Bl^T + Al@Bh^T  (fp32-accurate), output split hi/lo.
// ---------------------------------------------------------------------------
__global__ __launch_bounds__(256) void gemm_split_k(
    const bf16* __restrict__ Ah, const bf16* __restrict__ Al,
    const bf16* __restrict__ Bh, const bf16* __restrict__ Bl,
    bf16* __restrict__ out_hi, bf16* __restrict__ out_lo, int M, int N, int K)
{
    __shared__ __align__(16) bf16 Ahs[128 * 32];
    __shared__ __align__(16) bf16 Als[128 * 32];
    __shared__ __align__(16) bf16 Bhs[128 * 32];
    __shared__ __align__(16) bf16 Bls[128 * 32];
    const int t = threadIdx.x;
    const int fr = t & 15, fq = (t >> 4) & 3;
    const int w = t >> 6, wm = w & 1, wn = w >> 1;
    const long mBase = (long)blockIdx.y * 128;
    const long nBase = (long)blockIdx.x * 128;

    f32x4 acc[4][4];
#pragma unroll
    for (int i = 0; i < 4; i++)
#pragma unroll
        for (int j = 0; j < 4; j++) acc[i][j] = (f32x4){0.f, 0.f, 0.f, 0.f};

    const int arow = t >> 2;
    const int akc  = (t & 3) * 8;
    const long ga0 = (mBase + arow) * (long)K + akc;
    const long ga1 = (mBase + arow + 64) * (long)K + akc;
    const long gb0 = (nBase + arow) * (long)K + akc;
    const long gb1 = (nBase + arow + 64) * (long)K + akc;

    const int aoff = (wm * 64 + fr) * 32 + fq * 8;
    const int boff = (wn * 64 + fr) * 32 + fq * 8;

    for (int kt = 0; kt < K; kt += 32) {
        const bf16x8 vah0 = *(const bf16x8*)(Ah + ga0 + kt);
        const bf16x8 vah1 = *(const bf16x8*)(Ah + ga1 + kt);
        const bf16x8 val0 = *(const bf16x8*)(Al + ga0 + kt);
        const bf16x8 val1 = *(const bf16x8*)(Al + ga1 + kt);
        const bf16x8 vbh0 = *(const bf16x8*)(Bh + gb0 + kt);
        const bf16x8 vbh1 = *(const bf16x8*)(Bh + gb1 + kt);
        const bf16x8 vbl0 = *(const bf16x8*)(Bl + gb0 + kt);
        const bf16x8 vbl1 = *(const bf16x8*)(Bl + gb1 + kt);
        *(bf16x8*)&Ahs[t * 8] = vah0;
        *(bf16x8*)&Ahs[(256 + t) * 8] = vah1;
        *(bf16x8*)&Als[t * 8] = val0;
        *(bf16x8*)&Als[(256 + t) * 8] = val1;
        *(bf16x8*)&Bhs[t * 8] = vbh0;
        *(bf16x8*)&Bhs[(256 + t) * 8] = vbh1;
        *(bf16x8*)&Bls[t * 8] = vbl0;
        *(bf16x8*)&Bls[(256 + t) * 8] = vbl1;
        __syncthreads();
        bf16x8 ah[4], al[4], bh[4], bl[4];
#pragma unroll
        for (int mt = 0; mt < 4; mt++) {
            ah[mt] = *(const bf16x8*)&Ahs[aoff + mt * 512];
            al[mt] = *(const bf16x8*)&Als[aoff + mt * 512];
        }
#pragma unroll
        for (int nt = 0; nt < 4; nt++) {
            bh[nt] = *(const bf16x8*)&Bhs[boff + nt * 512];
            bl[nt] = *(const bf16x8*)&Bls[boff + nt * 512];
        }
#pragma unroll
        for (int mt = 0; mt < 4; mt++)
#pragma unroll
            for (int nt = 0; nt < 4; nt++) {
                acc[mt][nt] = MFMA16(ah[mt], bh[nt], acc[mt][nt]);
                acc[mt][nt] = MFMA16(ah[mt], bl[nt], acc[mt][nt]);
                acc[mt][nt] = MFMA16(al[mt], bh[nt], acc[mt][nt]);
            }
        __syncthreads();
    }

    const long crow0 = mBase + wm * 64;
    const long ccol0 = nBase + wn * 64;
#pragma unroll
    for (int nt = 0; nt < 4; nt++) {
        const long col = ccol0 + nt * 16 + fr;
#pragma unroll
        for (int mt = 0; mt < 4; mt++)
#pragma unroll
            for (int r = 0; r < 4; r++) {
                const long rowg = crow0 + mt * 16 + fq * 4 + r;
                const float v = acc[mt][nt][r];
                const long idx = rowg * (long)N + col;
                const bf16 h = (bf16)v;
                out_hi[idx] = h;
                out_lo[idx] = (bf16)(v - (float)h);
            }
    }
}

// ---------------------------------------------------------------------------
// Flash attention, split-precision QK^T. Per block: one (b,h), 64 q-rows
// (4 waves x 16). K-tiles of 64 keys. vt pre-transposed: [bh][d=128][S=2048].
// scores = (qh*kh + qh*kl + ql*kh) * sqrt(128) + mask*(-1e9); online softmax.
// ---------------------------------------------------------------------------
__global__ __launch_bounds__(256) void flash_attn_k(
    const bf16* __restrict__ qhi, const bf16* __restrict__ qlo,
    const bf16* __restrict__ khi, const bf16* __restrict__ klo,
    const bf16* __restrict__ vt, const float* __restrict__ mask,
    bf16* __restrict__ ctx)
{
    __shared__ __align__(16) bf16 Kh[64 * 128];
    __shared__ __align__(16) bf16 Kl[64 * 128];
    __shared__ __align__(16) bf16 Vs[128 * 64];
    __shared__ __align__(16) bf16 Ps[4][16 * 64];
    const float scale = 11.3137085f;  // sqrt(128) — faithful *sqrt(d) bug
    const int t = threadIdx.x, w = t >> 6;
    const int fr = t & 15, fq = (t >> 4) & 3;
    const int blk = blockIdx.x;
    const int qt = blk & 31, bh_ = blk >> 5, b = bh_ >> 3, h = bh_ & 7;
    const int qrow0 = qt * 64 + w * 16;

    const long qoff = ((long)(b * 2048 + qrow0 + fr)) * 1024 + h * 128 + fq * 8;
    bf16x8 qh[4], ql[4];
#pragma unroll
    for (int s = 0; s < 4; s++) {
        qh[s] = *(const bf16x8*)(qhi + qoff + s * 32);
        ql[s] = *(const bf16x8*)(qlo + qoff + s * 32);
    }
    f32x4 o[8];
#pragma unroll
    for (int nt = 0; nt < 8; nt++) o[nt] = (f32x4){0.f, 0.f, 0.f, 0.f};
    float m_run[4] = {-1e30f, -1e30f, -1e30f, -1e30f};
    float l_run[4] = {0.f, 0.f, 0.f, 0.f};
    const float* maskb = mask + b * 2048;

    const long kbase = (long)(b * 2048) * 1024 + h * 128 + (long)(t & 15) * 8;
    const long vbase = ((long)bh_ * 128) * 2048 + (long)(t & 7) * 8;

    for (int kt = 0; kt < 32; kt++) {
        __syncthreads();  // previous iteration's LDS readers done
#pragma unroll
        for (int i = 0; i < 4; i++) {
            const int key = i * 16 + (t >> 4);
            const long g = kbase + (long)(kt * 64 + key) * 1024;
            const bf16x8 vk_h = *(const bf16x8*)(khi + g);
            const bf16x8 vk_l = *(const bf16x8*)(klo + g);
            const int d = i * 32 + (t >> 3);
            const bf16x8 vv = *(const bf16x8*)(vt + vbase + (long)d * 2048 + kt * 64);
            *(bf16x8*)&Kh[(i * 256 + t) * 8] = vk_h;
            *(bf16x8*)&Kl[(i * 256 + t) * 8] = vk_l;
            *(bf16x8*)&Vs[(i * 256 + t) * 8] = vv;
        }
        __syncthreads();

        f32x4 sc[4];
#pragma unroll
        for (int ct = 0; ct < 4; ct++) {
            f32x4 a = (f32x4){0.f, 0.f, 0.f, 0.f};
#pragma unroll
            for (int s = 0; s < 4; s++) {
                const int off = (ct * 16 + fr) * 128 + s * 32 + fq * 8;
                const bf16x8 kh8 = *(const bf16x8*)&Kh[off];
                const bf16x8 kl8 = *(const bf16x8*)&Kl[off];
                a = MFMA16(qh[s], kh8, a);
                a = MFMA16(qh[s], kl8, a);
                a = MFMA16(ql[s], kh8, a);
            }
            sc[ct] = a;
        }
        float madd[4];
#pragma unroll
        for (int ct = 0; ct < 4; ct++)
            madd[ct] = maskb[kt * 64 + ct * 16 + fr] * (-1e9f);

        float alpha[4];
#pragma unroll
        for (int r = 0; r < 4; r++) {
            float mx = sc[0][r] * scale + madd[0];
            mx = fmaxf(mx, sc[1][r] * scale + madd[1]);
            mx = fmaxf(mx, sc[2][r] * scale + madd[2]);
            mx = fmaxf(mx, sc[3][r] * scale + madd[3]);
            mx = fmaxf(mx, __shfl_xor(mx, 1));
            mx = fmaxf(mx, __shfl_xor(mx, 2));
            mx = fmaxf(mx, __shfl_xor(mx, 4));
            mx = fmaxf(mx, __shfl_xor(mx, 8));
            const float mn = fmaxf(m_run[r], mx);
            alpha[r] = __expf(m_run[r] - mn);
            m_run[r] = mn;
        }
        float lt[4] = {0.f, 0.f, 0.f, 0.f};
#pragma unroll
        for (int ct = 0; ct < 4; ct++)
#pragma unroll
            for (int r = 0; r < 4; r++) {
                const float p = __expf(sc[ct][r] * scale + madd[ct] - m_run[r]);
                lt[r] += p;
                Ps[w][(fq * 4 + r) * 64 + ct * 16 + fr] = (bf16)p;
            }
#pragma unroll
        for (int r = 0; r < 4; r++) {
            float s_ = lt[r];
            s_ += __shfl_xor(s_, 1); s_ += __shfl_xor(s_, 2);
            s_ += __shfl_xor(s_, 4); s_ += __shfl_xor(s_, 8);
            l_run[r] = l_run[r] * alpha[r] + s_;
        }
#pragma unroll
        for (int nt = 0; nt < 8; nt++)
#pragma unroll
            for (int r = 0; r < 4; r++) o[nt][r] *= alpha[r];

#pragma unroll
        for (int sp = 0; sp < 2; sp++) {
            const bf16x8 pf = *(const bf16x8*)&Ps[w][fr * 64 + sp * 32 + fq * 8];
#pragma unroll
            for (int nt = 0; nt < 8; nt++) {
                const bf16x8 vf = *(const bf16x8*)&Vs[(nt * 16 + fr) * 64 + sp * 32 + fq * 8];
                o[nt] = MFMA16(pf, vf, o[nt]);
            }
        }
    }
#pragma unroll
    for (int r = 0; r < 4; r++) {
        const float inv = l_run[r] > 0.f ? 1.0f / l_run[r] : 0.f;
#pragma unroll
        for (int nt = 0; nt < 8; nt++) {
            const long idx = ((long)(b * 2048 + qrow0 + fq * 4 + r)) * 1024 + h * 128 + nt * 16 + fr;
            ctx[idx] = (bf16)(o[nt][r] * inv);
        }
    }
}

// ---------------------------------------------------------------------------
// Fused residual + LayerNorm: out = LN(res + y)*gamma + beta.
// res from fp32 xf if non-null else bf16 xb. OUTPUT: fp32 (float4 stores).
// ---------------------------------------------------------------------------
__global__ __launch_bounds__(256) void add_ln_k(
    const float* __restrict__ xf, const bf16* __restrict__ xb,
    const bf16* __restrict__ y,
    const float* __restrict__ gamma, const float* __restrict__ beta,
    float* __restrict__ out)
{
    __shared__ float red[8];
    const long row = blockIdx.x;
    const int t = threadIdx.x, lane = t & 63, w = t >> 6;
    float v[4];
    if (xf) {
        const float4 xv = *(const float4*)(xf + row * 1024 + t * 4);
        v[0] = xv.x; v[1] = xv.y; v[2] = xv.z; v[3] = xv.w;
    } else {
        const bf16x4 xv = *(const bf16x4*)(xb + row * 1024 + t * 4);
#pragma unroll
        for (int i = 0; i < 4; i++) v[i] = (float)xv[i];
    }
    const bf16x4 yv = *(const bf16x4*)(y + row * 1024 + t * 4);
    float s = 0.f, s2 = 0.f;
#pragma unroll
    for (int i = 0; i < 4; i++) {
        v[i] += (float)yv[i];
        s += v[i]; s2 += v[i] * v[i];
    }
#pragma unroll
    for (int off = 1; off < 64; off <<= 1) {
        s += __shfl_xor(s, off);
        s2 += __shfl_xor(s2, off);
    }
    if (lane == 0) { red[w] = s; red[4 + w] = s2; }
    __syncthreads();
    s = red[0] + red[1] + red[2] + red[3];
    s2 = red[4] + red[5] + red[6] + red[7];
    const float mean = s * (1.0f / 1024.0f);
    const float var = s2 * (1.0f / 1024.0f) - mean * mean;
    const float rstd = rsqrtf(var + 1e-6f);
    float4 ov;
    ov.x = (v[0] - mean) * rstd * gamma[t * 4 + 0] + beta[t * 4 + 0];
    ov.y = (v[1] - mean) * rstd * gamma[t * 4 + 1] + beta[t * 4 + 1];
    ov.z = (v[2] - mean) * rstd * gamma[t * 4 + 2] + beta[t * 4 + 2];
    ov.w = (v[3] - mean) * rstd * gamma[t * 4 + 3] + beta[t * 4 + 3];
    *(float4*)(out + row * 1024 + t * 4) = ov;
}

// ---------------------------------------------------------------------------
// x1 (fp32, for residual 2) also needs a bf16 copy for the FFN GEMM A-input.
// ---------------------------------------------------------------------------
__global__ __launch_bounds__(256) void f32_to_bf16_k(
    const float* __restrict__ in, bf16* __restrict__ out)
{
    const long i = (long)blockIdx.x * 256 + threadIdx.x;
    const float4 v = *(const float4*)(in + i * 4);
    bf16x4 h;
    h[0] = (bf16)v.x; h[1] = (bf16)v.y; h[2] = (bf16)v.z; h[3] = (bf16)v.w;
    *(bf16x4*)(out + i * 4) = h;
}

// ===========================================================================
extern "C" void kernel_launch(void* const* d_in, const int* in_sizes, int n_in,
                              void* d_out, int out_size, void* d_ws, size_t ws_size,
                              hipStream_t stream)
{
    (void)in_sizes; (void)n_in; (void)out_size; (void)ws_size;
    const float* x     = (const float*)d_in[0];
    const float* mask  = (const float*)d_in[1];
    const float* Wq    = (const float*)d_in[2];
    const float* Wk    = (const float*)d_in[3];
    const float* Wv    = (const float*)d_in[4];
    const float* Wo    = (const float*)d_in[5];
    const float* W1    = (const float*)d_in[6];
    const float* b1    = (const float*)d_in[7];
    const float* W2    = (const float*)d_in[8];
    const float* b2    = (const float*)d_in[9];
    const float* gamma = (const float*)d_in[10];
    const float* beta  = (const float*)d_in[11];
    float* out = (float*)d_out;   // fp32 output per reference dtype

    char* ws = (char*)d_ws;
    const size_t SZ = 8192ul * 1024 * 2;           // 16 MiB per [8192,1024] bf16
    bf16* qhi  = (bf16*)(ws + 0 * SZ);
    bf16* qlo  = (bf16*)(ws + 1 * SZ);
    bf16* khi  = (bf16*)(ws + 2 * SZ);
    bf16* klo  = (bf16*)(ws + 3 * SZ);
    bf16* hbuf = (bf16*)(ws + 0 * SZ);             // [8192,4096] aliases q/k (dead post-attn)
    bf16* vbuf = (bf16*)(ws + 4 * SZ);
    bf16* ctxb = vbuf;                             // aliases v (dead after vt built)
    bf16* vtb  = (bf16*)(ws + 5 * SZ);
    bf16* fbuf = vtb;                              // aliases vt (dead post-attn)
    bf16* xh   = (bf16*)(ws + 6 * SZ);
    bf16* xl   = (bf16*)(ws + 7 * SZ);
    bf16* aob  = xl;                               // aliases xl (dead after Q/K proj)
    float* x1f = (float*)(ws + 8 * SZ);            // fp32 x1 [8192,1024] = 32 MiB -> [128,160)
    bf16* x1b  = (bf16*)(ws + 10 * SZ);            // bf16 x1 [160,176)
    char* wts  = ws + 11 * SZ;                     // 176 MiB so far
    bf16* Wqth = (bf16*)(wts);
    bf16* Wqtl = (bf16*)(wts + 1 * 2097152);
    bf16* Wkth = (bf16*)(wts + 2 * 2097152);
    bf16* Wktl = (bf16*)(wts + 3 * 2097152);
    bf16* Wvt  = (bf16*)(wts + 4 * 2097152);
    bf16* Wot  = (bf16*)(wts + 5 * 2097152);
    bf16* W1t  = (bf16*)(wts + 6 * 2097152);
    bf16* W2t  = (bf16*)(wts + 6 * 2097152 + 8388608);
    // total ws use: 176 MiB + 12 MiB + 16 MiB = 204 MiB

    const dim3 blk(256);
    // x -> hi/lo bf16 split
    split_f32_k<<<dim3(8192), blk, 0, stream>>>(x, xh, xl);
    // weight transposes -> [N][K] bf16 (naive, correctness-first)
    naive_tr_w_k<<<dim3(4096), blk, 0, stream>>>(Wq, Wqth, Wqtl, 1024, 1024);
    naive_tr_w_k<<<dim3(4096), blk, 0, stream>>>(Wk, Wkth, Wktl, 1024, 1024);
    naive_tr_w_k<<<dim3(4096), blk, 0, stream>>>(Wv, Wvt, nullptr, 1024, 1024);
    naive_tr_w_k<<<dim3(4096), blk, 0, stream>>>(Wo, Wot, nullptr, 1024, 1024);
    naive_tr_w_k<<<dim3(16384), blk, 0, stream>>>(W1, W1t, nullptr, 1024, 4096);
    naive_tr_w_k<<<dim3(16384), blk, 0, stream>>>(W2, W2t, nullptr, 4096, 1024);
    // Q/K projections in split precision (fp32-accurate logits); V plain bf16
    gemm_split_k<<<dim3(8, 64), blk, 0, stream>>>(xh, xl, Wqth, Wqtl, qhi, qlo, 8192, 1024, 1024);
    gemm_split_k<<<dim3(8, 64), blk, 0, stream>>>(xh, xl, Wkth, Wktl, khi, klo, 8192, 1024, 1024);
    gemm_bf16_k<<<dim3(8, 64), blk, 0, stream>>>(xh, Wvt, vbuf, nullptr, 0, 8192, 1024, 1024);
    // per-head V transpose: [b*2048+s][h*128+d] -> [bh][d][s]
    naive_tr_v_k<<<dim3(1024, 1, 32), blk, 0, stream>>>(vbuf, vtb);
    flash_attn_k<<<dim3(1024), blk, 0, stream>>>(qhi, qlo, khi, klo, vtb, mask, ctxb);
    gemm_bf16_k<<<dim3(8, 64), blk, 0, stream>>>(ctxb, Wot, aob, nullptr, 0, 8192, 1024, 1024);
    // x1 = LN(x + attn_out): fp32 master copy + bf16 copy for GEMM A
    add_ln_k<<<dim3(8192), blk, 0, stream>>>(x, nullptr, aob, gamma, beta, x1f);
    f32_to_bf16_k<<<dim3(8192), blk, 0, stream>>>(x1f, x1b);
    gemm_bf16_k<<<dim3(32, 64), blk, 0, stream>>>(x1b, W1t, hbuf, b1, 1, 8192, 4096, 1024);
    gemm_bf16_k<<<dim3(8, 64), blk, 0, stream>>>(hbuf, W2t, fbuf, b2, 0, 8192, 1024, 4096);
    // out = LN(x1 + ffn) in fp32
    add_ln_k<<<dim3(8192), blk, 0, stream>>>(x1f, nullptr, fbuf, gamma, beta, out);
}

// Round 5
// 950.204 us; speedup vs baseline: 1.1555x; 1.1555x over previous
//
#include <hip/hip_runtime.h>

// ============================================================================
// EncoderLayer: x -> MHA(+residual,LN) -> FFN(+residual,LN)
// B=4 S=2048 H=1024 F=4096 nh=8 d=128. Inputs fp32, OUTPUT fp32.
// Core compute bf16 MFMA; Q/K path split hi/lo bf16 (faithful *sqrt(d) bug).
// R5: (a) flash LDS rows padded (K:136, V/P:72) to kill 16-way bank conflicts
//     (R4 profile: SQ_LDS_BANK_CONFLICT=1.5e8 ~ 55% of flash cycles);
//     (b) GEMMs back on m97 global_load_lds(16B) staging (exonerated by R2/R3).
// ============================================================================

typedef __bf16 bf16;
typedef __bf16 bf16x4 __attribute__((ext_vector_type(4)));
typedef __bf16 bf16x8 __attribute__((ext_vector_type(8)));
typedef float  f32x4  __attribute__((ext_vector_type(4)));

#define MFMA16(a, b, c) __builtin_amdgcn_mfma_f32_16x16x32_bf16(a, b, c, 0, 0, 0)

typedef const __attribute__((address_space(1))) void* gas_cptr;
typedef __attribute__((address_space(3))) void* las_ptr;

__device__ __forceinline__ void g2l16(const void* g, void* l) {
    // async global->LDS, 16B/lane; LDS dest = wave-uniform base + lane*16
    __builtin_amdgcn_global_load_lds((gas_cptr)g, (las_ptr)l, 16, 0, 0);
}

// ---------------------------------------------------------------------------
// x (fp32) -> hi/lo bf16 split. One float4 per thread.
// ---------------------------------------------------------------------------
__global__ __launch_bounds__(256) void split_f32_k(
    const float* __restrict__ in, bf16* __restrict__ hi, bf16* __restrict__ lo)
{
    const long i = (long)blockIdx.x * 256 + threadIdx.x;
    const float4 v = *(const float4*)(in + i * 4);
    const float a[4] = {v.x, v.y, v.z, v.w};
    bf16x4 h, l;
#pragma unroll
    for (int j = 0; j < 4; j++) {
        h[j] = (bf16)a[j];
        l[j] = (bf16)(a[j] - (float)h[j]);
    }
    *(bf16x4*)(hi + i * 4) = h;
    *(bf16x4*)(lo + i * 4) = l;
}

// ---------------------------------------------------------------------------
// Naive fp32 [R][C] -> bf16 [C][R] transpose (hi + optional lo residual).
// ---------------------------------------------------------------------------
__global__ __launch_bounds__(256) void naive_tr_w_k(
    const float* __restrict__ in, bf16* __restrict__ out_hi,
    bf16* __restrict__ out_lo, int R, int C)
{
    const long idx = (long)blockIdx.x * 256 + threadIdx.x;
    if (idx >= (long)R * C) return;
    const int r = (int)(idx / C);
    const int c = (int)(idx % C);
    const float v = in[idx];
    const bf16 h = (bf16)v;
    out_hi[(long)c * R + r] = h;
    if (out_lo) out_lo[(long)c * R + r] = (bf16)(v - (float)h);
}

// ---------------------------------------------------------------------------
// Naive per-head V transpose: vbuf[b*2048+s][h*128+dd] -> vt[bh][dd][s].
// ---------------------------------------------------------------------------
__global__ __launch_bounds__(256) void naive_tr_v_k(
    const bf16* __restrict__ in, bf16* __restrict__ out)
{
    const int z = blockIdx.z;              // bh = b*8+h
    const int b = z >> 3, h = z & 7;
    const int idx = blockIdx.x * 256 + threadIdx.x;   // over 2048*128
    const int s = idx >> 7, dd = idx & 127;
    const bf16 v = in[(long)(b * 2048 + s) * 1024 + h * 128 + dd];
    out[(long)z * 128 * 2048 + (long)dd * 2048 + s] = v;
}

// ---------------------------------------------------------------------------
// GEMM: C[M,N] = A[M,K] @ Bt[N,K]^T  (bf16, fp32 acc). m97 recipe: 128x128
// tile, BK=32, global_load_lds(16B), 4 waves x (64x64 = 4x4 MFMA).
// ---------------------------------------------------------------------------
__global__ __launch_bounds__(256) void gemm_bf16_k(
    const bf16* __restrict__ A, const bf16* __restrict__ Bt,
    bf16* __restrict__ out,
    const float* __restrict__ bias, int relu, int M, int N, int K)
{
    __shared__ __align__(16) bf16 As[128 * 32];
    __shared__ __align__(16) bf16 Bs[128 * 32];
    const int t = threadIdx.x;
    const int fr = t & 15, fq = (t >> 4) & 3;
    const int w = t >> 6, wm = w & 1, wn = w >> 1;
    const long mBase = (long)blockIdx.y * 128;
    const long nBase = (long)blockIdx.x * 128;

    f32x4 acc[4][4];
#pragma unroll
    for (int i = 0; i < 4; i++)
#pragma unroll
        for (int j = 0; j < 4; j++) acc[i][j] = (f32x4){0.f, 0.f, 0.f, 0.f};

    const int arow = t >> 2;
    const int akc  = (t & 3) * 8;
    const bf16* ga0 = A + (mBase + arow) * (long)K + akc;
    const bf16* ga1 = A + (mBase + arow + 64) * (long)K + akc;
    const bf16* gb0 = Bt + (nBase + arow) * (long)K + akc;
    const bf16* gb1 = Bt + (nBase + arow + 64) * (long)K + akc;
    bf16* la0 = &As[t * 8];
    bf16* la1 = &As[(256 + t) * 8];
    bf16* lb0 = &Bs[t * 8];
    bf16* lb1 = &Bs[(256 + t) * 8];

    const int aoff = (wm * 64 + fr) * 32 + fq * 8;
    const int boff = (wn * 64 + fr) * 32 + fq * 8;

    for (int kt = 0; kt < K; kt += 32) {
        g2l16(ga0 + kt, la0);
        g2l16(ga1 + kt, la1);
        g2l16(gb0 + kt, lb0);
        g2l16(gb1 + kt, lb1);
        __syncthreads();   // compiler drains vmcnt(0) before s_barrier
        bf16x8 af[4], bfv[4];
#pragma unroll
        for (int mt = 0; mt < 4; mt++) af[mt] = *(const bf16x8*)&As[aoff + mt * 512];
#pragma unroll
        for (int nt = 0; nt < 4; nt++) bfv[nt] = *(const bf16x8*)&Bs[boff + nt * 512];
#pragma unroll
        for (int mt = 0; mt < 4; mt++)
#pragma unroll
            for (int nt = 0; nt < 4; nt++)
                acc[mt][nt] = MFMA16(af[mt], bfv[nt], acc[mt][nt]);
        __syncthreads();
    }

    const long crow0 = mBase + wm * 64;
    const long ccol0 = nBase + wn * 64;
#pragma unroll
    for (int nt = 0; nt < 4; nt++) {
        const long col = ccol0 + nt * 16 + fr;
        const float bv = bias ? bias[col] : 0.0f;
#pragma unroll
        for (int mt = 0; mt < 4; mt++)
#pragma unroll
            for (int r = 0; r < 4; r++) {
                const long rowg = crow0 + mt * 16 + fq * 4 + r;  // C/D: col=lane&15, row=quad*4+reg
                float v = acc[mt][nt][r] + bv;
                if (relu) v = fmaxf(v, 0.0f);
                out[rowg * (long)N + col] = (bf16)v;
            }
    }
}

// ---------------------------------------------------------------------------
// Split-precision GEMM for Q/K projections:
//   C = Ah@Bh^T + Ah@Bl^T + Al@Bh^T  (fp32-accurate), output split hi/lo.
// ---------------------------------------------------------------------------
__global__ __launch_bounds__(256) void gemm_split_k(
    const bf16* __restrict__ Ah, const bf16* __restrict__ Al,
    const bf16* __restrict__ Bh, const bf16* __restrict__ Bl,
    bf16* __restrict__ out_hi, bf16* __restrict__ out_lo, int M, int N, int K)
{
    __shared__ __align__(16) bf16 Ahs[128 * 32];
    __shared__ __align__(16) bf16 Als[128 * 32];
    __shared__ __align__(16) bf16 Bhs[128 * 32];
    __shared__ __align__(16) bf16 Bls[128 * 32];
    const int t = threadIdx.x;
    const int fr = t & 15, fq = (t >> 4) & 3;
    const int w = t >> 6, wm = w & 1, wn = w >> 1;
    const long mBase = (long)blockIdx.y * 128;
    const long nBase = (long)blockIdx.x * 128;

    f32x4 acc[4][4];
#pragma unroll
    for (int i = 0; i < 4; i++)
#pragma unroll
        for (int j = 0; j < 4; j++) acc[i][j] = (f32x4){0.f, 0.f, 0.f, 0.f};

    const int arow = t >> 2;
    const int akc  = (t & 3) * 8;
    const long ga0 = (mBase + arow) * (long)K + akc;
    const long ga1 = (mBase + arow + 64) * (long)K + akc;
    const long gb0 = (nBase + arow) * (long)K + akc;
    const long gb1 = (nBase + arow + 64) * (long)K + akc;

    const int aoff = (wm * 64 + fr) * 32 + fq * 8;
    const int boff = (wn * 64 + fr) * 32 + fq * 8;

    for (int kt = 0; kt < K; kt += 32) {
        g2l16(Ah + ga0 + kt, &Ahs[t * 8]);
        g2l16(Ah + ga1 + kt, &Ahs[(256 + t) * 8]);
        g2l16(Al + ga0 + kt, &Als[t * 8]);
        g2l16(Al + ga1 + kt, &Als[(256 + t) * 8]);
        g2l16(Bh + gb0 + kt, &Bhs[t * 8]);
        g2l16(Bh + gb1 + kt, &Bhs[(256 + t) * 8]);
        g2l16(Bl + gb0 + kt, &Bls[t * 8]);
        g2l16(Bl + gb1 + kt, &Bls[(256 + t) * 8]);
        __syncthreads();
        bf16x8 ah[4], al[4], bh[4], bl[4];
#pragma unroll
        for (int mt = 0; mt < 4; mt++) {
            ah[mt] = *(const bf16x8*)&Ahs[aoff + mt * 512];
            al[mt] = *(const bf16x8*)&Als[aoff + mt * 512];
        }
#pragma unroll
        for (int nt = 0; nt < 4; nt++) {
            bh[nt] = *(const bf16x8*)&Bhs[boff + nt * 512];
            bl[nt] = *(const bf16x8*)&Bls[boff + nt * 512];
        }
#pragma unroll
        for (int mt = 0; mt < 4; mt++)
#pragma unroll
            for (int nt = 0; nt < 4; nt++) {
                acc[mt][nt] = MFMA16(ah[mt], bh[nt], acc[mt][nt]);
                acc[mt][nt] = MFMA16(ah[mt], bl[nt], acc[mt][nt]);
                acc[mt][nt] = MFMA16(al[mt], bh[nt], acc[mt][nt]);
            }
        __syncthreads();
    }

    const long crow0 = mBase + wm * 64;
    const long ccol0 = nBase + wn * 64;
#pragma unroll
    for (int nt = 0; nt < 4; nt++) {
        const long col = ccol0 + nt * 16 + fr;
#pragma unroll
        for (int mt = 0; mt < 4; mt++)
#pragma unroll
            for (int r = 0; r < 4; r++) {
                const long rowg = crow0 + mt * 16 + fq * 4 + r;
                const float v = acc[mt][nt][r];
                const long idx = rowg * (long)N + col;
                const bf16 h = (bf16)v;
                out_hi[idx] = h;
                out_lo[idx] = (bf16)(v - (float)h);
            }
    }
}

// ---------------------------------------------------------------------------
// Flash attention, split-precision QK^T. Per block: one (b,h), 64 q-rows
// (4 waves x 16). K-tiles of 64 keys. vt pre-transposed: [bh][d=128][S=2048].
// LDS rows PADDED: K rows 136 (=128+8), V/P rows 72 (=64+8) -> byte stride
// 272/144 (16B-aligned, stride mod 32 dwords = 4) => 2-way bank aliasing
// (free) instead of 16-way. Register staging (g2l16 can't target padded dst).
// ---------------------------------------------------------------------------
#define KROW 136
#define VROW 72
#define PROW 72
__global__ __launch_bounds__(256) void flash_attn_k(
    const bf16* __restrict__ qhi, const bf16* __restrict__ qlo,
    const bf16* __restrict__ khi, const bf16* __restrict__ klo,
    const bf16* __restrict__ vt, const float* __restrict__ mask,
    bf16* __restrict__ ctx)
{
    __shared__ __align__(16) bf16 Kh[64 * KROW];
    __shared__ __align__(16) bf16 Kl[64 * KROW];
    __shared__ __align__(16) bf16 Vs[128 * VROW];
    __shared__ __align__(16) bf16 Ps[4][16 * PROW];
    const float scale = 11.3137085f;  // sqrt(128) — faithful *sqrt(d) bug
    const int t = threadIdx.x, w = t >> 6;
    const int fr = t & 15, fq = (t >> 4) & 3;
    const int blk = blockIdx.x;
    const int qt = blk & 31, bh_ = blk >> 5, b = bh_ >> 3, h = bh_ & 7;
    const int qrow0 = qt * 64 + w * 16;

    const long qoff = ((long)(b * 2048 + qrow0 + fr)) * 1024 + h * 128 + fq * 8;
    bf16x8 qh[4], ql[4];
#pragma unroll
    for (int s = 0; s < 4; s++) {
        qh[s] = *(const bf16x8*)(qhi + qoff + s * 32);
        ql[s] = *(const bf16x8*)(qlo + qoff + s * 32);
    }
    f32x4 o[8];
#pragma unroll
    for (int nt = 0; nt < 8; nt++) o[nt] = (f32x4){0.f, 0.f, 0.f, 0.f};
    float m_run[4] = {-1e30f, -1e30f, -1e30f, -1e30f};
    float l_run[4] = {0.f, 0.f, 0.f, 0.f};
    const float* maskb = mask + b * 2048;

    const long kbase = (long)(b * 2048) * 1024 + h * 128 + (long)(t & 15) * 8;
    const long vbase = ((long)bh_ * 128) * 2048 + (long)(t & 7) * 8;

    for (int kt = 0; kt < 32; kt++) {
        __syncthreads();  // previous iteration's LDS readers done
#pragma unroll
        for (int i = 0; i < 4; i++) {
            const int key = i * 16 + (t >> 4);
            const long g = kbase + (long)(kt * 64 + key) * 1024;
            const bf16x8 vk_h = *(const bf16x8*)(khi + g);
            const bf16x8 vk_l = *(const bf16x8*)(klo + g);
            const int d = i * 32 + (t >> 3);
            const bf16x8 vv = *(const bf16x8*)(vt + vbase + (long)d * 2048 + kt * 64);
            *(bf16x8*)&Kh[key * KROW + (t & 15) * 8] = vk_h;
            *(bf16x8*)&Kl[key * KROW + (t & 15) * 8] = vk_l;
            *(bf16x8*)&Vs[d * VROW + (t & 7) * 8] = vv;
        }
        __syncthreads();

        f32x4 sc[4];
#pragma unroll
        for (int ct = 0; ct < 4; ct++) {
            f32x4 a = (f32x4){0.f, 0.f, 0.f, 0.f};
#pragma unroll
            for (int s = 0; s < 4; s++) {
                const int off = (ct * 16 + fr) * KROW + s * 32 + fq * 8;
                const bf16x8 kh8 = *(const bf16x8*)&Kh[off];
                const bf16x8 kl8 = *(const bf16x8*)&Kl[off];
                a = MFMA16(qh[s], kh8, a);
                a = MFMA16(qh[s], kl8, a);
                a = MFMA16(ql[s], kh8, a);
            }
            sc[ct] = a;
        }
        float madd[4];
#pragma unroll
        for (int ct = 0; ct < 4; ct++)
            madd[ct] = maskb[kt * 64 + ct * 16 + fr] * (-1e9f);

        float alpha[4];
#pragma unroll
        for (int r = 0; r < 4; r++) {
            float mx = sc[0][r] * scale + madd[0];
            mx = fmaxf(mx, sc[1][r] * scale + madd[1]);
            mx = fmaxf(mx, sc[2][r] * scale + madd[2]);
            mx = fmaxf(mx, sc[3][r] * scale + madd[3]);
            mx = fmaxf(mx, __shfl_xor(mx, 1));
            mx = fmaxf(mx, __shfl_xor(mx, 2));
            mx = fmaxf(mx, __shfl_xor(mx, 4));
            mx = fmaxf(mx, __shfl_xor(mx, 8));
            const float mn = fmaxf(m_run[r], mx);
            alpha[r] = __expf(m_run[r] - mn);
            m_run[r] = mn;
        }
        float lt[4] = {0.f, 0.f, 0.f, 0.f};
#pragma unroll
        for (int ct = 0; ct < 4; ct++)
#pragma unroll
            for (int r = 0; r < 4; r++) {
                const float p = __expf(sc[ct][r] * scale + madd[ct] - m_run[r]);
                lt[r] += p;
                Ps[w][(fq * 4 + r) * PROW + ct * 16 + fr] = (bf16)p;
            }
#pragma unroll
        for (int r = 0; r < 4; r++) {
            float s_ = lt[r];
            s_ += __shfl_xor(s_, 1); s_ += __shfl_xor(s_, 2);
            s_ += __shfl_xor(s_, 4); s_ += __shfl_xor(s_, 8);
            l_run[r] = l_run[r] * alpha[r] + s_;
        }
#pragma unroll
        for (int nt = 0; nt < 8; nt++)
#pragma unroll
            for (int r = 0; r < 4; r++) o[nt][r] *= alpha[r];

#pragma unroll
        for (int sp = 0; sp < 2; sp++) {
            const bf16x8 pf = *(const bf16x8*)&Ps[w][fr * PROW + sp * 32 + fq * 8];
#pragma unroll
            for (int nt = 0; nt < 8; nt++) {
                const bf16x8 vf = *(const bf16x8*)&Vs[(nt * 16 + fr) * VROW + sp * 32 + fq * 8];
                o[nt] = MFMA16(pf, vf, o[nt]);
            }
        }
    }
#pragma unroll
    for (int r = 0; r < 4; r++) {
        const float inv = l_run[r] > 0.f ? 1.0f / l_run[r] : 0.f;
#pragma unroll
        for (int nt = 0; nt < 8; nt++) {
            const long idx = ((long)(b * 2048 + qrow0 + fq * 4 + r)) * 1024 + h * 128 + nt * 16 + fr;
            ctx[idx] = (bf16)(o[nt][r] * inv);
        }
    }
}

// ---------------------------------------------------------------------------
// Fused residual + LayerNorm: out = LN(res + y)*gamma + beta (fp32 out).
// res from fp32 xf if non-null else bf16 xb.
// ---------------------------------------------------------------------------
__global__ __launch_bounds__(256) void add_ln_k(
    const float* __restrict__ xf, const bf16* __restrict__ xb,
    const bf16* __restrict__ y,
    const float* __restrict__ gamma, const float* __restrict__ beta,
    float* __restrict__ out)
{
    __shared__ float red[8];
    const long row = blockIdx.x;
    const int t = threadIdx.x, lane = t & 63, w = t >> 6;
    float v[4];
    if (xf) {
        const float4 xv = *(const float4*)(xf + row * 1024 + t * 4);
        v[0] = xv.x; v[1] = xv.y; v[2] = xv.z; v[3] = xv.w;
    } else {
        const bf16x4 xv = *(const bf16x4*)(xb + row * 1024 + t * 4);
#pragma unroll
        for (int i = 0; i < 4; i++) v[i] = (float)xv[i];
    }
    const bf16x4 yv = *(const bf16x4*)(y + row * 1024 + t * 4);
    float s = 0.f, s2 = 0.f;
#pragma unroll
    for (int i = 0; i < 4; i++) {
        v[i] += (float)yv[i];
        s += v[i]; s2 += v[i] * v[i];
    }
#pragma unroll
    for (int off = 1; off < 64; off <<= 1) {
        s += __shfl_xor(s, off);
        s2 += __shfl_xor(s2, off);
    }
    if (lane == 0) { red[w] = s; red[4 + w] = s2; }
    __syncthreads();
    s = red[0] + red[1] + red[2] + red[3];
    s2 = red[4] + red[5] + red[6] + red[7];
    const float mean = s * (1.0f / 1024.0f);
    const float var = s2 * (1.0f / 1024.0f) - mean * mean;
    const float rstd = rsqrtf(var + 1e-6f);
    float4 ov;
    ov.x = (v[0] - mean) * rstd * gamma[t * 4 + 0] + beta[t * 4 + 0];
    ov.y = (v[1] - mean) * rstd * gamma[t * 4 + 1] + beta[t * 4 + 1];
    ov.z = (v[2] - mean) * rstd * gamma[t * 4 + 2] + beta[t * 4 + 2];
    ov.w = (v[3] - mean) * rstd * gamma[t * 4 + 3] + beta[t * 4 + 3];
    *(float4*)(out + row * 1024 + t * 4) = ov;
}

// ---------------------------------------------------------------------------
// fp32 -> bf16 copy (x1 master copy feeds FFN GEMM A-input as bf16).
// ---------------------------------------------------------------------------
__global__ __launch_bounds__(256) void f32_to_bf16_k(
    const float* __restrict__ in, bf16* __restrict__ out)
{
    const long i = (long)blockIdx.x * 256 + threadIdx.x;
    const float4 v = *(const float4*)(in + i * 4);
    bf16x4 h;
    h[0] = (bf16)v.x; h[1] = (bf16)v.y; h[2] = (bf16)v.z; h[3] = (bf16)v.w;
    *(bf16x4*)(out + i * 4) = h;
}

// ===========================================================================
extern "C" void kernel_launch(void* const* d_in, const int* in_sizes, int n_in,
                              void* d_out, int out_size, void* d_ws, size_t ws_size,
                              hipStream_t stream)
{
    (void)in_sizes; (void)n_in; (void)out_size; (void)ws_size;
    const float* x     = (const float*)d_in[0];
    const float* mask  = (const float*)d_in[1];
    const float* Wq    = (const float*)d_in[2];
    const float* Wk    = (const float*)d_in[3];
    const float* Wv    = (const float*)d_in[4];
    const float* Wo    = (const float*)d_in[5];
    const float* W1    = (const float*)d_in[6];
    const float* b1    = (const float*)d_in[7];
    const float* W2    = (const float*)d_in[8];
    const float* b2    = (const float*)d_in[9];
    const float* gamma = (const float*)d_in[10];
    const float* beta  = (const float*)d_in[11];
    float* out = (float*)d_out;   // fp32 output per reference dtype

    char* ws = (char*)d_ws;
    const size_t SZ = 8192ul * 1024 * 2;           // 16 MiB per [8192,1024] bf16
    bf16* qhi  = (bf16*)(ws + 0 * SZ);
    bf16* qlo  = (bf16*)(ws + 1 * SZ);
    bf16* khi  = (bf16*)(ws + 2 * SZ);
    bf16* klo  = (bf16*)(ws + 3 * SZ);
    bf16* hbuf = (bf16*)(ws + 0 * SZ);             // [8192,4096] aliases q/k (dead post-attn)
    bf16* vbuf = (bf16*)(ws + 4 * SZ);
    bf16* ctxb = vbuf;                             // aliases v (dead after vt built)
    bf16* vtb  = (bf16*)(ws + 5 * SZ);
    bf16* fbuf = vtb;                              // aliases vt (dead post-attn)
    bf16* xh   = (bf16*)(ws + 6 * SZ);
    bf16* xl   = (bf16*)(ws + 7 * SZ);
    bf16* aob  = xl;                               // aliases xl (dead after Q/K proj)
    float* x1f = (float*)(ws + 8 * SZ);            // fp32 x1 [8192,1024] = 32 MiB
    bf16* x1b  = (bf16*)(ws + 10 * SZ);
    char* wts  = ws + 11 * SZ;                     // 176 MiB so far
    bf16* Wqth = (bf16*)(wts);
    bf16* Wqtl = (bf16*)(wts + 1 * 2097152);
    bf16* Wkth = (bf16*)(wts + 2 * 2097152);
    bf16* Wktl = (bf16*)(wts + 3 * 2097152);
    bf16* Wvt  = (bf16*)(wts + 4 * 2097152);
    bf16* Wot  = (bf16*)(wts + 5 * 2097152);
    bf16* W1t  = (bf16*)(wts + 6 * 2097152);
    bf16* W2t  = (bf16*)(wts + 6 * 2097152 + 8388608);
    // total ws use: ~204 MiB

    const dim3 blk(256);
    // x -> hi/lo bf16 split
    split_f32_k<<<dim3(8192), blk, 0, stream>>>(x, xh, xl);
    // weight transposes -> [N][K] bf16 (naive)
    naive_tr_w_k<<<dim3(4096), blk, 0, stream>>>(Wq, Wqth, Wqtl, 1024, 1024);
    naive_tr_w_k<<<dim3(4096), blk, 0, stream>>>(Wk, Wkth, Wktl, 1024, 1024);
    naive_tr_w_k<<<dim3(4096), blk, 0, stream>>>(Wv, Wvt, nullptr, 1024, 1024);
    naive_tr_w_k<<<dim3(4096), blk, 0, stream>>>(Wo, Wot, nullptr, 1024, 1024);
    naive_tr_w_k<<<dim3(16384), blk, 0, stream>>>(W1, W1t, nullptr, 1024, 4096);
    naive_tr_w_k<<<dim3(16384), blk, 0, stream>>>(W2, W2t, nullptr, 4096, 1024);
    // Q/K projections in split precision (fp32-accurate logits); V plain bf16
    gemm_split_k<<<dim3(8, 64), blk, 0, stream>>>(xh, xl, Wqth, Wqtl, qhi, qlo, 8192, 1024, 1024);
    gemm_split_k<<<dim3(8, 64), blk, 0, stream>>>(xh, xl, Wkth, Wktl, khi, klo, 8192, 1024, 1024);
    gemm_bf16_k<<<dim3(8, 64), blk, 0, stream>>>(xh, Wvt, vbuf, nullptr, 0, 8192, 1024, 1024);
    // per-head V transpose: [b*2048+s][h*128+d] -> [bh][d][s]
    naive_tr_v_k<<<dim3(1024, 1, 32), blk, 0, stream>>>(vbuf, vtb);
    flash_attn_k<<<dim3(1024), blk, 0, stream>>>(qhi, qlo, khi, klo, vtb, mask, ctxb);
    gemm_bf16_k<<<dim3(8, 64), blk, 0, stream>>>(ctxb, Wot, aob, nullptr, 0, 8192, 1024, 1024);
    // x1 = LN(x + attn_out): fp32 master + bf16 copy for GEMM A
    add_ln_k<<<dim3(8192), blk, 0, stream>>>(x, nullptr, aob, gamma, beta, x1f);
    f32_to_bf16_k<<<dim3(8192), blk, 0, stream>>>(x1f, x1b);
    gemm_bf16_k<<<dim3(32, 64), blk, 0, stream>>>(x1b, W1t, hbuf, b1, 1, 8192, 4096, 1024);
    gemm_bf16_k<<<dim3(8, 64), blk, 0, stream>>>(hbuf, W2t, fbuf, b2, 0, 8192, 1024, 4096);
    // out = LN(x1 + ffn) in fp32
    add_ln_k<<<dim3(8192), blk, 0, stream>>>(x1f, nullptr, fbuf, gamma, beta, out);
}

// Round 6
// 906.435 us; speedup vs baseline: 1.2113x; 1.0483x over previous
//
#include <hip/hip_runtime.h>

// ============================================================================
// EncoderLayer: x -> MHA(+residual,LN) -> FFN(+residual,LN)
// B=4 S=2048 H=1024 F=4096 nh=8 d=128. Inputs fp32, OUTPUT fp32.
// Core compute bf16 MFMA; Q/K path split hi/lo bf16 (faithful *sqrt(d) bug).
// R6: flash Q-tile 128 (2 m-tiles/wave -> LDS K/V read per q-row halved,
//     512 blocks), mask staged to LDS; LDS-tiled transposes restored
//     (R2-exonerated); f32->bf16 copy fused into add_ln.
// ============================================================================

typedef __bf16 bf16;
typedef __bf16 bf16x4 __attribute__((ext_vector_type(4)));
typedef __bf16 bf16x8 __attribute__((ext_vector_type(8)));
typedef float  f32x4  __attribute__((ext_vector_type(4)));

#define MFMA16(a, b, c) __builtin_amdgcn_mfma_f32_16x16x32_bf16(a, b, c, 0, 0, 0)

typedef const __attribute__((address_space(1))) void* gas_cptr;
typedef __attribute__((address_space(3))) void* las_ptr;

__device__ __forceinline__ void g2l16(const void* g, void* l) {
    __builtin_amdgcn_global_load_lds((gas_cptr)g, (las_ptr)l, 16, 0, 0);
}

__device__ __forceinline__ uint b16bits(bf16 v) {
    union { bf16 h; unsigned short u; } cv; cv.h = v; return (uint)cv.u;
}

// ---------------------------------------------------------------------------
// x (fp32) -> hi/lo bf16 split. One float4 per thread.
// ---------------------------------------------------------------------------
__global__ __launch_bounds__(256) void split_f32_k(
    const float* __restrict__ in, bf16* __restrict__ hi, bf16* __restrict__ lo)
{
    const long i = (long)blockIdx.x * 256 + threadIdx.x;
    const float4 v = *(const float4*)(in + i * 4);
    const float a[4] = {v.x, v.y, v.z, v.w};
    bf16x4 h, l;
#pragma unroll
    for (int j = 0; j < 4; j++) {
        h[j] = (bf16)a[j];
        l[j] = (bf16)(a[j] - (float)h[j]);
    }
    *(bf16x4*)(hi + i * 4) = h;
    *(bf16x4*)(lo + i * 4) = l;
}

// ---------------------------------------------------------------------------
// fp32 [R][C] -> bf16 [C][R] transpose (hi + optional lo residual).
// 64x64 tiles, u32 row-pair packing in LDS (conflict-free). [R2-exonerated]
// ---------------------------------------------------------------------------
__global__ __launch_bounds__(256) void transpose_f32_k(
    const float* __restrict__ in, bf16* __restrict__ out_hi, bf16* __restrict__ out_lo,
    int in_rs, int out_rs)
{
    __shared__ uint Th[64][33];
    __shared__ uint Tl[64][33];
    const long c0 = (long)blockIdx.x * 64;
    const long r0 = (long)blockIdx.y * 64;
    const int t = threadIdx.x, rp = t >> 3, cc = t & 7;
    const float* pa = in + (r0 + 2 * rp) * (long)in_rs + c0 + cc * 8;
    const float* pb = pa + in_rs;
    float a[8], b[8];
    *(float4*)&a[0] = *(const float4*)pa;
    *(float4*)&a[4] = *(const float4*)(pa + 4);
    *(float4*)&b[0] = *(const float4*)pb;
    *(float4*)&b[4] = *(const float4*)(pb + 4);
#pragma unroll
    for (int j = 0; j < 8; j++) {
        const bf16 ah = (bf16)a[j], bh = (bf16)b[j];
        Th[cc * 8 + j][rp] = b16bits(ah) | (b16bits(bh) << 16);
        const bf16 al = (bf16)(a[j] - (float)ah), bl = (bf16)(b[j] - (float)bh);
        Tl[cc * 8 + j][rp] = b16bits(al) | (b16bits(bl) << 16);
    }
    __syncthreads();
#pragma unroll
    for (int i = 0; i < 2; i++) {
        const int task = i * 256 + t;
        const int c = task >> 3, ch = task & 7;
        uint4 wv;
        wv.x = Th[c][ch * 4 + 0]; wv.y = Th[c][ch * 4 + 1];
        wv.z = Th[c][ch * 4 + 2]; wv.w = Th[c][ch * 4 + 3];
        *(uint4*)(out_hi + (c0 + c) * (long)out_rs + r0 + ch * 8) = wv;
        if (out_lo) {
            uint4 wl;
            wl.x = Tl[c][ch * 4 + 0]; wl.y = Tl[c][ch * 4 + 1];
            wl.z = Tl[c][ch * 4 + 2]; wl.w = Tl[c][ch * 4 + 3];
            *(uint4*)(out_lo + (c0 + c) * (long)out_rs + r0 + ch * 8) = wl;
        }
    }
}

// ---------------------------------------------------------------------------
// bf16 [R][C] -> bf16 [C][R] transpose (per-head V). [R2-exonerated]
// batch z: in_off = (z/nh)*bo_in + (z%nh)*bi_in ; out_off = z*bo_out
// ---------------------------------------------------------------------------
__global__ __launch_bounds__(256) void transpose_bf16_k(
    const bf16* __restrict__ in, bf16* __restrict__ out,
    int in_rs, int out_rs, int nh, long bo_in, long bi_in, long bo_out)
{
    __shared__ uint T[64][33];
    const int z = blockIdx.z;
    const bf16* inp = in + (long)(z / nh) * bo_in + (long)(z % nh) * bi_in;
    bf16* outp = out + (long)z * bo_out;
    const long c0 = (long)blockIdx.x * 64;
    const long r0 = (long)blockIdx.y * 64;
    const int t = threadIdx.x, rp = t >> 3, cc = t & 7;

    const uint4 ra = *(const uint4*)(inp + (r0 + 2 * rp) * (long)in_rs + c0 + cc * 8);
    const uint4 rb = *(const uint4*)(inp + (r0 + 2 * rp + 1) * (long)in_rs + c0 + cc * 8);
    const uint a32[4] = {ra.x, ra.y, ra.z, ra.w};
    const uint b32[4] = {rb.x, rb.y, rb.z, rb.w};
#pragma unroll
    for (int j = 0; j < 8; j++) {
        const uint av = (j & 1) ? (a32[j >> 1] >> 16) : (a32[j >> 1] & 0xffffu);
        const uint bv = (j & 1) ? (b32[j >> 1] >> 16) : (b32[j >> 1] & 0xffffu);
        T[cc * 8 + j][rp] = av | (bv << 16);
    }
    __syncthreads();
#pragma unroll
    for (int i = 0; i < 2; i++) {
        const int task = i * 256 + t;
        const int c = task >> 3, ch = task & 7;
        uint4 wv;
        wv.x = T[c][ch * 4 + 0]; wv.y = T[c][ch * 4 + 1];
        wv.z = T[c][ch * 4 + 2]; wv.w = T[c][ch * 4 + 3];
        *(uint4*)(outp + (c0 + c) * (long)out_rs + r0 + ch * 8) = wv;
    }
}

// ---------------------------------------------------------------------------
// GEMM: C[M,N] = A[M,K] @ Bt[N,K]^T  (bf16, fp32 acc). m97 recipe.
// ---------------------------------------------------------------------------
__global__ __launch_bounds__(256) void gemm_bf16_k(
    const bf16* __restrict__ A, const bf16* __restrict__ Bt,
    bf16* __restrict__ out,
    const float* __restrict__ bias, int relu, int M, int N, int K)
{
    __shared__ __align__(16) bf16 As[128 * 32];
    __shared__ __align__(16) bf16 Bs[128 * 32];
    const int t = threadIdx.x;
    const int fr = t & 15, fq = (t >> 4) & 3;
    const int w = t >> 6, wm = w & 1, wn = w >> 1;
    const long mBase = (long)blockIdx.y * 128;
    const long nBase = (long)blockIdx.x * 128;

    f32x4 acc[4][4];
#pragma unroll
    for (int i = 0; i < 4; i++)
#pragma unroll
        for (int j = 0; j < 4; j++) acc[i][j] = (f32x4){0.f, 0.f, 0.f, 0.f};

    const int arow = t >> 2;
    const int akc  = (t & 3) * 8;
    const bf16* ga0 = A + (mBase + arow) * (long)K + akc;
    const bf16* ga1 = A + (mBase + arow + 64) * (long)K + akc;
    const bf16* gb0 = Bt + (nBase + arow) * (long)K + akc;
    const bf16* gb1 = Bt + (nBase + arow + 64) * (long)K + akc;
    bf16* la0 = &As[t * 8];
    bf16* la1 = &As[(256 + t) * 8];
    bf16* lb0 = &Bs[t * 8];
    bf16* lb1 = &Bs[(256 + t) * 8];

    const int aoff = (wm * 64 + fr) * 32 + fq * 8;
    const int boff = (wn * 64 + fr) * 32 + fq * 8;

    for (int kt = 0; kt < K; kt += 32) {
        g2l16(ga0 + kt, la0);
        g2l16(ga1 + kt, la1);
        g2l16(gb0 + kt, lb0);
        g2l16(gb1 + kt, lb1);
        __syncthreads();
        bf16x8 af[4], bfv[4];
#pragma unroll
        for (int mt = 0; mt < 4; mt++) af[mt] = *(const bf16x8*)&As[aoff + mt * 512];
#pragma unroll
        for (int nt = 0; nt < 4; nt++) bfv[nt] = *(const bf16x8*)&Bs[boff + nt * 512];
#pragma unroll
        for (int mt = 0; mt < 4; mt++)
#pragma unroll
            for (int nt = 0; nt < 4; nt++)
                acc[mt][nt] = MFMA16(af[mt], bfv[nt], acc[mt][nt]);
        __syncthreads();
    }

    const long crow0 = mBase + wm * 64;
    const long ccol0 = nBase + wn * 64;
#pragma unroll
    for (int nt = 0; nt < 4; nt++) {
        const long col = ccol0 + nt * 16 + fr;
        const float bv = bias ? bias[col] : 0.0f;
#pragma unroll
        for (int mt = 0; mt < 4; mt++)
#pragma unroll
            for (int r = 0; r < 4; r++) {
                const long rowg = crow0 + mt * 16 + fq * 4 + r;
                float v = acc[mt][nt][r] + bv;
                if (relu) v = fmaxf(v, 0.0f);
                out[rowg * (long)N + col] = (bf16)v;
            }
    }
}

// ---------------------------------------------------------------------------
// Split-precision GEMM (Q/K): C = Ah@Bh^T + Ah@Bl^T + Al@Bh^T, split out.
// ---------------------------------------------------------------------------
__global__ __launch_bounds__(256) void gemm_split_k(
    const bf16* __restrict__ Ah, const bf16* __restrict__ Al,
    const bf16* __restrict__ Bh, const bf16* __restrict__ Bl,
    bf16* __restrict__ out_hi, bf16* __restrict__ out_lo, int M, int N, int K)
{
    __shared__ __align__(16) bf16 Ahs[128 * 32];
    __shared__ __align__(16) bf16 Als[128 * 32];
    __shared__ __align__(16) bf16 Bhs[128 * 32];
    __shared__ __align__(16) bf16 Bls[128 * 32];
    const int t = threadIdx.x;
    const int fr = t & 15, fq = (t >> 4) & 3;
    const int w = t >> 6, wm = w & 1, wn = w >> 1;
    const long mBase = (long)blockIdx.y * 128;
    const long nBase = (long)blockIdx.x * 128;

    f32x4 acc[4][4];
#pragma unroll
    for (int i = 0; i < 4; i++)
#pragma unroll
        for (int j = 0; j < 4; j++) acc[i][j] = (f32x4){0.f, 0.f, 0.f, 0.f};

    const int arow = t >> 2;
    const int akc  = (t & 3) * 8;
    const long ga0 = (mBase + arow) * (long)K + akc;
    const long ga1 = (mBase + arow + 64) * (long)K + akc;
    const long gb0 = (nBase + arow) * (long)K + akc;
    const long gb1 = (nBase + arow + 64) * (long)K + akc;

    const int aoff = (wm * 64 + fr) * 32 + fq * 8;
    const int boff = (wn * 64 + fr) * 32 + fq * 8;

    for (int kt = 0; kt < K; kt += 32) {
        g2l16(Ah + ga0 + kt, &Ahs[t * 8]);
        g2l16(Ah + ga1 + kt, &Ahs[(256 + t) * 8]);
        g2l16(Al + ga0 + kt, &Als[t * 8]);
        g2l16(Al + ga1 + kt, &Als[(256 + t) * 8]);
        g2l16(Bh + gb0 + kt, &Bhs[t * 8]);
        g2l16(Bh + gb1 + kt, &Bhs[(256 + t) * 8]);
        g2l16(Bl + gb0 + kt, &Bls[t * 8]);
        g2l16(Bl + gb1 + kt, &Bls[(256 + t) * 8]);
        __syncthreads();
        bf16x8 ah[4], al[4], bh[4], bl[4];
#pragma unroll
        for (int mt = 0; mt < 4; mt++) {
            ah[mt] = *(const bf16x8*)&Ahs[aoff + mt * 512];
            al[mt] = *(const bf16x8*)&Als[aoff + mt * 512];
        }
#pragma unroll
        for (int nt = 0; nt < 4; nt++) {
            bh[nt] = *(const bf16x8*)&Bhs[boff + nt * 512];
            bl[nt] = *(const bf16x8*)&Bls[boff + nt * 512];
        }
#pragma unroll
        for (int mt = 0; mt < 4; mt++)
#pragma unroll
            for (int nt = 0; nt < 4; nt++) {
                acc[mt][nt] = MFMA16(ah[mt], bh[nt], acc[mt][nt]);
                acc[mt][nt] = MFMA16(ah[mt], bl[nt], acc[mt][nt]);
                acc[mt][nt] = MFMA16(al[mt], bh[nt], acc[mt][nt]);
            }
        __syncthreads();
    }

    const long crow0 = mBase + wm * 64;
    const long ccol0 = nBase + wn * 64;
#pragma unroll
    for (int nt = 0; nt < 4; nt++) {
        const long col = ccol0 + nt * 16 + fr;
#pragma unroll
        for (int mt = 0; mt < 4; mt++)
#pragma unroll
            for (int r = 0; r < 4; r++) {
                const long rowg = crow0 + mt * 16 + fq * 4 + r;
                const float v = acc[mt][nt][r];
                const long idx = rowg * (long)N + col;
                const bf16 h = (bf16)v;
                out_hi[idx] = h;
                out_lo[idx] = (bf16)(v - (float)h);
            }
    }
}

// ---------------------------------------------------------------------------
// Flash attention v2: Q-tile 128 rows/block (each wave 2 m-tiles of 16),
// 512 blocks, 64-key LDS tiles, split-precision QK^T, mask row in LDS.
// Padded LDS rows (K:136, V/P:72) -> 2-way bank aliasing (free).
// ---------------------------------------------------------------------------
#define KROW 136
#define VROW 72
#define PROW 72
__global__ __launch_bounds__(256) void flash_attn_k(
    const bf16* __restrict__ qhi, const bf16* __restrict__ qlo,
    const bf16* __restrict__ khi, const bf16* __restrict__ klo,
    const bf16* __restrict__ vt, const float* __restrict__ mask,
    bf16* __restrict__ ctx)
{
    __shared__ __align__(16) bf16 Kh[64 * KROW];
    __shared__ __align__(16) bf16 Kl[64 * KROW];
    __shared__ __align__(16) bf16 Vs[128 * VROW];
    __shared__ __align__(16) bf16 Ps[4][2][16 * PROW];
    __shared__ __align__(16) float Ms[2048];
    const float scale = 11.3137085f;  // sqrt(128) — faithful *sqrt(d) bug
    const int t = threadIdx.x, w = t >> 6;
    const int fr = t & 15, fq = (t >> 4) & 3;
    const int blk = blockIdx.x;
    const int qt = blk & 15, bh_ = blk >> 4, b = bh_ >> 3, h = bh_ & 7;
    const int qrow0 = qt * 128 + w * 16;   // wave rows: qrow0 + mt*64 + (0..15)

    // stage mask row (2048 fp32 = 8 KiB) once
    {
        const float4* mrow = (const float4*)(mask + b * 2048);
        ((float4*)Ms)[t] = mrow[t];
        ((float4*)Ms)[256 + t] = mrow[256 + t];
    }

    bf16x8 qh[2][4], ql[2][4];
#pragma unroll
    for (int mt = 0; mt < 2; mt++) {
        const long qoff = ((long)(b * 2048 + qrow0 + mt * 64 + fr)) * 1024 + h * 128 + fq * 8;
#pragma unroll
        for (int s = 0; s < 4; s++) {
            qh[mt][s] = *(const bf16x8*)(qhi + qoff + s * 32);
            ql[mt][s] = *(const bf16x8*)(qlo + qoff + s * 32);
        }
    }
    f32x4 o[2][8];
#pragma unroll
    for (int mt = 0; mt < 2; mt++)
#pragma unroll
        for (int nt = 0; nt < 8; nt++) o[mt][nt] = (f32x4){0.f, 0.f, 0.f, 0.f};
    float m_run[2][4], l_run[2][4];
#pragma unroll
    for (int mt = 0; mt < 2; mt++)
#pragma unroll
        for (int r = 0; r < 4; r++) { m_run[mt][r] = -1e30f; l_run[mt][r] = 0.f; }

    const long kbase = (long)(b * 2048) * 1024 + h * 128 + (long)(t & 15) * 8;
    const long vbase = ((long)bh_ * 128) * 2048 + (long)(t & 7) * 8;

    for (int kt = 0; kt < 32; kt++) {
        __syncthreads();
#pragma unroll
        for (int i = 0; i < 4; i++) {
            const int key = i * 16 + (t >> 4);
            const long g = kbase + (long)(kt * 64 + key) * 1024;
            const bf16x8 vk_h = *(const bf16x8*)(khi + g);
            const bf16x8 vk_l = *(const bf16x8*)(klo + g);
            const int d = i * 32 + (t >> 3);
            const bf16x8 vv = *(const bf16x8*)(vt + vbase + (long)d * 2048 + kt * 64);
            *(bf16x8*)&Kh[key * KROW + (t & 15) * 8] = vk_h;
            *(bf16x8*)&Kl[key * KROW + (t & 15) * 8] = vk_l;
            *(bf16x8*)&Vs[d * VROW + (t & 7) * 8] = vv;
        }
        __syncthreads();

        // QK^T: shared K-fragment reads feed both m-tiles
        f32x4 sc[2][4];
#pragma unroll
        for (int mt = 0; mt < 2; mt++)
#pragma unroll
            for (int ct = 0; ct < 4; ct++) sc[mt][ct] = (f32x4){0.f, 0.f, 0.f, 0.f};
#pragma unroll
        for (int ct = 0; ct < 4; ct++)
#pragma unroll
            for (int s = 0; s < 4; s++) {
                const int off = (ct * 16 + fr) * KROW + s * 32 + fq * 8;
                const bf16x8 kh8 = *(const bf16x8*)&Kh[off];
                const bf16x8 kl8 = *(const bf16x8*)&Kl[off];
#pragma unroll
                for (int mt = 0; mt < 2; mt++) {
                    sc[mt][ct] = MFMA16(qh[mt][s], kh8, sc[mt][ct]);
                    sc[mt][ct] = MFMA16(qh[mt][s], kl8, sc[mt][ct]);
                    sc[mt][ct] = MFMA16(ql[mt][s], kh8, sc[mt][ct]);
                }
            }
        float madd[4];
#pragma unroll
        for (int ct = 0; ct < 4; ct++)
            madd[ct] = Ms[kt * 64 + ct * 16 + fr] * (-1e9f);

#pragma unroll
        for (int mt = 0; mt < 2; mt++) {
            float alpha[4];
#pragma unroll
            for (int r = 0; r < 4; r++) {
                float mx = sc[mt][0][r] * scale + madd[0];
                mx = fmaxf(mx, sc[mt][1][r] * scale + madd[1]);
                mx = fmaxf(mx, sc[mt][2][r] * scale + madd[2]);
                mx = fmaxf(mx, sc[mt][3][r] * scale + madd[3]);
                mx = fmaxf(mx, __shfl_xor(mx, 1));
                mx = fmaxf(mx, __shfl_xor(mx, 2));
                mx = fmaxf(mx, __shfl_xor(mx, 4));
                mx = fmaxf(mx, __shfl_xor(mx, 8));
                const float mn = fmaxf(m_run[mt][r], mx);
                alpha[r] = __expf(m_run[mt][r] - mn);
                m_run[mt][r] = mn;
            }
            float lt[4] = {0.f, 0.f, 0.f, 0.f};
#pragma unroll
            for (int ct = 0; ct < 4; ct++)
#pragma unroll
                for (int r = 0; r < 4; r++) {
                    const float p = __expf(sc[mt][ct][r] * scale + madd[ct] - m_run[mt][r]);
                    lt[r] += p;
                    Ps[w][mt][(fq * 4 + r) * PROW + ct * 16 + fr] = (bf16)p;
                }
#pragma unroll
            for (int r = 0; r < 4; r++) {
                float s_ = lt[r];
                s_ += __shfl_xor(s_, 1); s_ += __shfl_xor(s_, 2);
                s_ += __shfl_xor(s_, 4); s_ += __shfl_xor(s_, 8);
                l_run[mt][r] = l_run[mt][r] * alpha[r] + s_;
            }
#pragma unroll
            for (int nt = 0; nt < 8; nt++)
#pragma unroll
                for (int r = 0; r < 4; r++) o[mt][nt][r] *= alpha[r];
        }

        // PV: shared V-fragment reads feed both m-tiles
#pragma unroll
        for (int sp = 0; sp < 2; sp++) {
            bf16x8 pf[2];
#pragma unroll
            for (int mt = 0; mt < 2; mt++)
                pf[mt] = *(const bf16x8*)&Ps[w][mt][fr * PROW + sp * 32 + fq * 8];
#pragma unroll
            for (int nt = 0; nt < 8; nt++) {
                const bf16x8 vf = *(const bf16x8*)&Vs[(nt * 16 + fr) * VROW + sp * 32 + fq * 8];
#pragma unroll
                for (int mt = 0; mt < 2; mt++)
                    o[mt][nt] = MFMA16(pf[mt], vf, o[mt][nt]);
            }
        }
    }
#pragma unroll
    for (int mt = 0; mt < 2; mt++)
#pragma unroll
        for (int r = 0; r < 4; r++) {
            const float inv = l_run[mt][r] > 0.f ? 1.0f / l_run[mt][r] : 0.f;
#pragma unroll
            for (int nt = 0; nt < 8; nt++) {
                const long idx = ((long)(b * 2048 + qrow0 + mt * 64 + fq * 4 + r)) * 1024
                               + h * 128 + nt * 16 + fr;
                ctx[idx] = (bf16)(o[mt][nt][r] * inv);
            }
        }
}

// ---------------------------------------------------------------------------
// Fused residual + LayerNorm: out = LN(xf + y)*gamma + beta (fp32 out,
// optional bf16 copy out_b for downstream GEMM A-input).
// ---------------------------------------------------------------------------
__global__ __launch_bounds__(256) void add_ln_k(
    const float* __restrict__ xf, const bf16* __restrict__ y,
    const float* __restrict__ gamma, const float* __restrict__ beta,
    float* __restrict__ out, bf16* __restrict__ out_b)
{
    __shared__ float red[8];
    const long row = blockIdx.x;
    const int t = threadIdx.x, lane = t & 63, w = t >> 6;
    float v[4];
    const float4 xv = *(const float4*)(xf + row * 1024 + t * 4);
    v[0] = xv.x; v[1] = xv.y; v[2] = xv.z; v[3] = xv.w;
    const bf16x4 yv = *(const bf16x4*)(y + row * 1024 + t * 4);
    float s = 0.f, s2 = 0.f;
#pragma unroll
    for (int i = 0; i < 4; i++) {
        v[i] += (float)yv[i];
        s += v[i]; s2 += v[i] * v[i];
    }
#pragma unroll
    for (int off = 1; off < 64; off <<= 1) {
        s += __shfl_xor(s, off);
        s2 += __shfl_xor(s2, off);
    }
    if (lane == 0) { red[w] = s; red[4 + w] = s2; }
    __syncthreads();
    s = red[0] + red[1] + red[2] + red[3];
    s2 = red[4] + red[5] + red[6] + red[7];
    const float mean = s * (1.0f / 1024.0f);
    const float var = s2 * (1.0f / 1024.0f) - mean * mean;
    const float rstd = rsqrtf(var + 1e-6f);
    float4 ov;
    ov.x = (v[0] - mean) * rstd * gamma[t * 4 + 0] + beta[t * 4 + 0];
    ov.y = (v[1] - mean) * rstd * gamma[t * 4 + 1] + beta[t * 4 + 1];
    ov.z = (v[2] - mean) * rstd * gamma[t * 4 + 2] + beta[t * 4 + 2];
    ov.w = (v[3] - mean) * rstd * gamma[t * 4 + 3] + beta[t * 4 + 3];
    *(float4*)(out + row * 1024 + t * 4) = ov;
    if (out_b) {
        bf16x4 hb;
        hb[0] = (bf16)ov.x; hb[1] = (bf16)ov.y; hb[2] = (bf16)ov.z; hb[3] = (bf16)ov.w;
        *(bf16x4*)(out_b + row * 1024 + t * 4) = hb;
    }
}

// ===========================================================================
extern "C" void kernel_launch(void* const* d_in, const int* in_sizes, int n_in,
                              void* d_out, int out_size, void* d_ws, size_t ws_size,
                              hipStream_t stream)
{
    (void)in_sizes; (void)n_in; (void)out_size; (void)ws_size;
    const float* x     = (const float*)d_in[0];
    const float* mask  = (const float*)d_in[1];
    const float* Wq    = (const float*)d_in[2];
    const float* Wk    = (const float*)d_in[3];
    const float* Wv    = (const float*)d_in[4];
    const float* Wo    = (const float*)d_in[5];
    const float* W1    = (const float*)d_in[6];
    const float* b1    = (const float*)d_in[7];
    const float* W2    = (const float*)d_in[8];
    const float* b2    = (const float*)d_in[9];
    const float* gamma = (const float*)d_in[10];
    const float* beta  = (const float*)d_in[11];
    float* out = (float*)d_out;   // fp32 output per reference dtype

    char* ws = (char*)d_ws;
    const size_t SZ = 8192ul * 1024 * 2;           // 16 MiB per [8192,1024] bf16
    bf16* qhi  = (bf16*)(ws + 0 * SZ);
    bf16* qlo  = (bf16*)(ws + 1 * SZ);
    bf16* khi  = (bf16*)(ws + 2 * SZ);
    bf16* klo  = (bf16*)(ws + 3 * SZ);
    bf16* hbuf = (bf16*)(ws + 0 * SZ);             // [8192,4096] aliases q/k (dead post-attn)
    bf16* vbuf = (bf16*)(ws + 4 * SZ);
    bf16* ctxb = vbuf;                             // aliases v (dead after vt built)
    bf16* vtb  = (bf16*)(ws + 5 * SZ);
    bf16* fbuf = vtb;                              // aliases vt (dead post-attn)
    bf16* xh   = (bf16*)(ws + 6 * SZ);
    bf16* xl   = (bf16*)(ws + 7 * SZ);
    bf16* aob  = xl;                               // aliases xl (dead after Q/K proj)
    float* x1f = (float*)(ws + 8 * SZ);            // fp32 x1 [8192,1024] = 32 MiB
    bf16* x1b  = (bf16*)(ws + 10 * SZ);
    char* wts  = ws + 11 * SZ;
    bf16* Wqth = (bf16*)(wts);
    bf16* Wqtl = (bf16*)(wts + 1 * 2097152);
    bf16* Wkth = (bf16*)(wts + 2 * 2097152);
    bf16* Wktl = (bf16*)(wts + 3 * 2097152);
    bf16* Wvt  = (bf16*)(wts + 4 * 2097152);
    bf16* Wot  = (bf16*)(wts + 5 * 2097152);
    bf16* W1t  = (bf16*)(wts + 6 * 2097152);
    bf16* W2t  = (bf16*)(wts + 6 * 2097152 + 8388608);

    const dim3 blk(256);
    split_f32_k<<<dim3(8192), blk, 0, stream>>>(x, xh, xl);
    // weight transposes -> [N][K] bf16, LDS-tiled
    transpose_f32_k<<<dim3(16, 16), blk, 0, stream>>>(Wq, Wqth, Wqtl, 1024, 1024);
    transpose_f32_k<<<dim3(16, 16), blk, 0, stream>>>(Wk, Wkth, Wktl, 1024, 1024);
    transpose_f32_k<<<dim3(16, 16), blk, 0, stream>>>(Wv, Wvt, nullptr, 1024, 1024);
    transpose_f32_k<<<dim3(16, 16), blk, 0, stream>>>(Wo, Wot, nullptr, 1024, 1024);
    transpose_f32_k<<<dim3(64, 16), blk, 0, stream>>>(W1, W1t, nullptr, 4096, 1024);
    transpose_f32_k<<<dim3(16, 64), blk, 0, stream>>>(W2, W2t, nullptr, 1024, 4096);
    // Q/K projections split-precision; V plain bf16
    gemm_split_k<<<dim3(8, 64), blk, 0, stream>>>(xh, xl, Wqth, Wqtl, qhi, qlo, 8192, 1024, 1024);
    gemm_split_k<<<dim3(8, 64), blk, 0, stream>>>(xh, xl, Wkth, Wktl, khi, klo, 8192, 1024, 1024);
    gemm_bf16_k<<<dim3(8, 64), blk, 0, stream>>>(xh, Wvt, vbuf, nullptr, 0, 8192, 1024, 1024);
    // per-head V transpose: [b*2048+s][h*128+d] -> [bh][d][s]
    transpose_bf16_k<<<dim3(2, 32, 32), blk, 0, stream>>>(vbuf, vtb, 1024, 2048, 8,
                                                          (long)2048 * 1024, 128L, (long)128 * 2048);
    flash_attn_k<<<dim3(512), blk, 0, stream>>>(qhi, qlo, khi, klo, vtb, mask, ctxb);
    gemm_bf16_k<<<dim3(8, 64), blk, 0, stream>>>(ctxb, Wot, aob, nullptr, 0, 8192, 1024, 1024);
    // x1 = LN(x + attn_out): fp32 master + fused bf16 copy
    add_ln_k<<<dim3(8192), blk, 0, stream>>>(x, aob, gamma, beta, x1f, x1b);
    gemm_bf16_k<<<dim3(32, 64), blk, 0, stream>>>(x1b, W1t, hbuf, b1, 1, 8192, 4096, 1024);
    gemm_bf16_k<<<dim3(8, 64), blk, 0, stream>>>(hbuf, W2t, fbuf, b2, 0, 8192, 1024, 4096);
    add_ln_k<<<dim3(8192), blk, 0, stream>>>(x1f, fbuf, gamma, beta, out, nullptr);
}

// Round 7
// 809.058 us; speedup vs baseline: 1.3571x; 1.1204x over previous
//
#include <hip/hip_runtime.h>

// ============================================================================
// EncoderLayer: x -> MHA(+residual,LN) -> FFN(+residual,LN)
// B=4 S=2048 H=1024 F=4096 nh=8 d=128. Inputs fp32, OUTPUT fp32.
// Core compute bf16 MFMA; Q/K path split hi/lo bf16 (faithful *sqrt(d) bug).
// R7: flash LDS 78->62.4 KB (Ps reused across m-tiles, mask from global) to
//     restore 2 blocks/CU (R6: 79872B -> occupancy 23%->12%, flash regressed
//     302->368 us). Q=128 shared K/V reads kept.
// ============================================================================

typedef __bf16 bf16;
typedef __bf16 bf16x4 __attribute__((ext_vector_type(4)));
typedef __bf16 bf16x8 __attribute__((ext_vector_type(8)));
typedef float  f32x4  __attribute__((ext_vector_type(4)));

#define MFMA16(a, b, c) __builtin_amdgcn_mfma_f32_16x16x32_bf16(a, b, c, 0, 0, 0)

typedef const __attribute__((address_space(1))) void* gas_cptr;
typedef __attribute__((address_space(3))) void* las_ptr;

__device__ __forceinline__ void g2l16(const void* g, void* l) {
    __builtin_amdgcn_global_load_lds((gas_cptr)g, (las_ptr)l, 16, 0, 0);
}

__device__ __forceinline__ uint b16bits(bf16 v) {
    union { bf16 h; unsigned short u; } cv; cv.h = v; return (uint)cv.u;
}

// ---------------------------------------------------------------------------
// x (fp32) -> hi/lo bf16 split. One float4 per thread.
// ---------------------------------------------------------------------------
__global__ __launch_bounds__(256) void split_f32_k(
    const float* __restrict__ in, bf16* __restrict__ hi, bf16* __restrict__ lo)
{
    const long i = (long)blockIdx.x * 256 + threadIdx.x;
    const float4 v = *(const float4*)(in + i * 4);
    const float a[4] = {v.x, v.y, v.z, v.w};
    bf16x4 h, l;
#pragma unroll
    for (int j = 0; j < 4; j++) {
        h[j] = (bf16)a[j];
        l[j] = (bf16)(a[j] - (float)h[j]);
    }
    *(bf16x4*)(hi + i * 4) = h;
    *(bf16x4*)(lo + i * 4) = l;
}

// ---------------------------------------------------------------------------
// fp32 [R][C] -> bf16 [C][R] transpose (hi + optional lo residual).
// 64x64 tiles, u32 row-pair packing in LDS (conflict-free).
// ---------------------------------------------------------------------------
__global__ __launch_bounds__(256) void transpose_f32_k(
    const float* __restrict__ in, bf16* __restrict__ out_hi, bf16* __restrict__ out_lo,
    int in_rs, int out_rs)
{
    __shared__ uint Th[64][33];
    __shared__ uint Tl[64][33];
    const long c0 = (long)blockIdx.x * 64;
    const long r0 = (long)blockIdx.y * 64;
    const int t = threadIdx.x, rp = t >> 3, cc = t & 7;
    const float* pa = in + (r0 + 2 * rp) * (long)in_rs + c0 + cc * 8;
    const float* pb = pa + in_rs;
    float a[8], b[8];
    *(float4*)&a[0] = *(const float4*)pa;
    *(float4*)&a[4] = *(const float4*)(pa + 4);
    *(float4*)&b[0] = *(const float4*)pb;
    *(float4*)&b[4] = *(const float4*)(pb + 4);
#pragma unroll
    for (int j = 0; j < 8; j++) {
        const bf16 ah = (bf16)a[j], bh = (bf16)b[j];
        Th[cc * 8 + j][rp] = b16bits(ah) | (b16bits(bh) << 16);
        const bf16 al = (bf16)(a[j] - (float)ah), bl = (bf16)(b[j] - (float)bh);
        Tl[cc * 8 + j][rp] = b16bits(al) | (b16bits(bl) << 16);
    }
    __syncthreads();
#pragma unroll
    for (int i = 0; i < 2; i++) {
        const int task = i * 256 + t;
        const int c = task >> 3, ch = task & 7;
        uint4 wv;
        wv.x = Th[c][ch * 4 + 0]; wv.y = Th[c][ch * 4 + 1];
        wv.z = Th[c][ch * 4 + 2]; wv.w = Th[c][ch * 4 + 3];
        *(uint4*)(out_hi + (c0 + c) * (long)out_rs + r0 + ch * 8) = wv;
        if (out_lo) {
            uint4 wl;
            wl.x = Tl[c][ch * 4 + 0]; wl.y = Tl[c][ch * 4 + 1];
            wl.z = Tl[c][ch * 4 + 2]; wl.w = Tl[c][ch * 4 + 3];
            *(uint4*)(out_lo + (c0 + c) * (long)out_rs + r0 + ch * 8) = wl;
        }
    }
}

// ---------------------------------------------------------------------------
// bf16 [R][C] -> bf16 [C][R] transpose (per-head V).
// batch z: in_off = (z/nh)*bo_in + (z%nh)*bi_in ; out_off = z*bo_out
// ---------------------------------------------------------------------------
__global__ __launch_bounds__(256) void transpose_bf16_k(
    const bf16* __restrict__ in, bf16* __restrict__ out,
    int in_rs, int out_rs, int nh, long bo_in, long bi_in, long bo_out)
{
    __shared__ uint T[64][33];
    const int z = blockIdx.z;
    const bf16* inp = in + (long)(z / nh) * bo_in + (long)(z % nh) * bi_in;
    bf16* outp = out + (long)z * bo_out;
    const long c0 = (long)blockIdx.x * 64;
    const long r0 = (long)blockIdx.y * 64;
    const int t = threadIdx.x, rp = t >> 3, cc = t & 7;

    const uint4 ra = *(const uint4*)(inp + (r0 + 2 * rp) * (long)in_rs + c0 + cc * 8);
    const uint4 rb = *(const uint4*)(inp + (r0 + 2 * rp + 1) * (long)in_rs + c0 + cc * 8);
    const uint a32[4] = {ra.x, ra.y, ra.z, ra.w};
    const uint b32[4] = {rb.x, rb.y, rb.z, rb.w};
#pragma unroll
    for (int j = 0; j < 8; j++) {
        const uint av = (j & 1) ? (a32[j >> 1] >> 16) : (a32[j >> 1] & 0xffffu);
        const uint bv = (j & 1) ? (b32[j >> 1] >> 16) : (b32[j >> 1] & 0xffffu);
        T[cc * 8 + j][rp] = av | (bv << 16);
    }
    __syncthreads();
#pragma unroll
    for (int i = 0; i < 2; i++) {
        const int task = i * 256 + t;
        const int c = task >> 3, ch = task & 7;
        uint4 wv;
        wv.x = T[c][ch * 4 + 0]; wv.y = T[c][ch * 4 + 1];
        wv.z = T[c][ch * 4 + 2]; wv.w = T[c][ch * 4 + 3];
        *(uint4*)(outp + (c0 + c) * (long)out_rs + r0 + ch * 8) = wv;
    }
}

// ---------------------------------------------------------------------------
// GEMM: C[M,N] = A[M,K] @ Bt[N,K]^T  (bf16, fp32 acc). m97 recipe.
// ---------------------------------------------------------------------------
__global__ __launch_bounds__(256) void gemm_bf16_k(
    const bf16* __restrict__ A, const bf16* __restrict__ Bt,
    bf16* __restrict__ out,
    const float* __restrict__ bias, int relu, int M, int N, int K)
{
    __shared__ __align__(16) bf16 As[128 * 32];
    __shared__ __align__(16) bf16 Bs[128 * 32];
    const int t = threadIdx.x;
    const int fr = t & 15, fq = (t >> 4) & 3;
    const int w = t >> 6, wm = w & 1, wn = w >> 1;
    const long mBase = (long)blockIdx.y * 128;
    const long nBase = (long)blockIdx.x * 128;

    f32x4 acc[4][4];
#pragma unroll
    for (int i = 0; i < 4; i++)
#pragma unroll
        for (int j = 0; j < 4; j++) acc[i][j] = (f32x4){0.f, 0.f, 0.f, 0.f};

    const int arow = t >> 2;
    const int akc  = (t & 3) * 8;
    const bf16* ga0 = A + (mBase + arow) * (long)K + akc;
    const bf16* ga1 = A + (mBase + arow + 64) * (long)K + akc;
    const bf16* gb0 = Bt + (nBase + arow) * (long)K + akc;
    const bf16* gb1 = Bt + (nBase + arow + 64) * (long)K + akc;
    bf16* la0 = &As[t * 8];
    bf16* la1 = &As[(256 + t) * 8];
    bf16* lb0 = &Bs[t * 8];
    bf16* lb1 = &Bs[(256 + t) * 8];

    const int aoff = (wm * 64 + fr) * 32 + fq * 8;
    const int boff = (wn * 64 + fr) * 32 + fq * 8;

    for (int kt = 0; kt < K; kt += 32) {
        g2l16(ga0 + kt, la0);
        g2l16(ga1 + kt, la1);
        g2l16(gb0 + kt, lb0);
        g2l16(gb1 + kt, lb1);
        __syncthreads();
        bf16x8 af[4], bfv[4];
#pragma unroll
        for (int mt = 0; mt < 4; mt++) af[mt] = *(const bf16x8*)&As[aoff + mt * 512];
#pragma unroll
        for (int nt = 0; nt < 4; nt++) bfv[nt] = *(const bf16x8*)&Bs[boff + nt * 512];
#pragma unroll
        for (int mt = 0; mt < 4; mt++)
#pragma unroll
            for (int nt = 0; nt < 4; nt++)
                acc[mt][nt] = MFMA16(af[mt], bfv[nt], acc[mt][nt]);
        __syncthreads();
    }

    const long crow0 = mBase + wm * 64;
    const long ccol0 = nBase + wn * 64;
#pragma unroll
    for (int nt = 0; nt < 4; nt++) {
        const long col = ccol0 + nt * 16 + fr;
        const float bv = bias ? bias[col] : 0.0f;
#pragma unroll
        for (int mt = 0; mt < 4; mt++)
#pragma unroll
            for (int r = 0; r < 4; r++) {
                const long rowg = crow0 + mt * 16 + fq * 4 + r;
                float v = acc[mt][nt][r] + bv;
                if (relu) v = fmaxf(v, 0.0f);
                out[rowg * (long)N + col] = (bf16)v;
            }
    }
}

// ---------------------------------------------------------------------------
// Split-precision GEMM (Q/K): C = Ah@Bh^T + Ah@Bl^T + Al@Bh^T, split out.
// ---------------------------------------------------------------------------
__global__ __launch_bounds__(256) void gemm_split_k(
    const bf16* __restrict__ Ah, const bf16* __restrict__ Al,
    const bf16* __restrict__ Bh, const bf16* __restrict__ Bl,
    bf16* __restrict__ out_hi, bf16* __restrict__ out_lo, int M, int N, int K)
{
    __shared__ __align__(16) bf16 Ahs[128 * 32];
    __shared__ __align__(16) bf16 Als[128 * 32];
    __shared__ __align__(16) bf16 Bhs[128 * 32];
    __shared__ __align__(16) bf16 Bls[128 * 32];
    const int t = threadIdx.x;
    const int fr = t & 15, fq = (t >> 4) & 3;
    const int w = t >> 6, wm = w & 1, wn = w >> 1;
    const long mBase = (long)blockIdx.y * 128;
    const long nBase = (long)blockIdx.x * 128;

    f32x4 acc[4][4];
#pragma unroll
    for (int i = 0; i < 4; i++)
#pragma unroll
        for (int j = 0; j < 4; j++) acc[i][j] = (f32x4){0.f, 0.f, 0.f, 0.f};

    const int arow = t >> 2;
    const int akc  = (t & 3) * 8;
    const long ga0 = (mBase + arow) * (long)K + akc;
    const long ga1 = (mBase + arow + 64) * (long)K + akc;
    const long gb0 = (nBase + arow) * (long)K + akc;
    const long gb1 = (nBase + arow + 64) * (long)K + akc;

    const int aoff = (wm * 64 + fr) * 32 + fq * 8;
    const int boff = (wn * 64 + fr) * 32 + fq * 8;

    for (int kt = 0; kt < K; kt += 32) {
        g2l16(Ah + ga0 + kt, &Ahs[t * 8]);
        g2l16(Ah + ga1 + kt, &Ahs[(256 + t) * 8]);
        g2l16(Al + ga0 + kt, &Als[t * 8]);
        g2l16(Al + ga1 + kt, &Als[(256 + t) * 8]);
        g2l16(Bh + gb0 + kt, &Bhs[t * 8]);
        g2l16(Bh + gb1 + kt, &Bhs[(256 + t) * 8]);
        g2l16(Bl + gb0 + kt, &Bls[t * 8]);
        g2l16(Bl + gb1 + kt, &Bls[(256 + t) * 8]);
        __syncthreads();
        bf16x8 ah[4], al[4], bh[4], bl[4];
#pragma unroll
        for (int mt = 0; mt < 4; mt++) {
            ah[mt] = *(const bf16x8*)&Ahs[aoff + mt * 512];
            al[mt] = *(const bf16x8*)&Als[aoff + mt * 512];
        }
#pragma unroll
        for (int nt = 0; nt < 4; nt++) {
            bh[nt] = *(const bf16x8*)&Bhs[boff + nt * 512];
            bl[nt] = *(const bf16x8*)&Bls[boff + nt * 512];
        }
#pragma unroll
        for (int mt = 0; mt < 4; mt++)
#pragma unroll
            for (int nt = 0; nt < 4; nt++) {
                acc[mt][nt] = MFMA16(ah[mt], bh[nt], acc[mt][nt]);
                acc[mt][nt] = MFMA16(ah[mt], bl[nt], acc[mt][nt]);
                acc[mt][nt] = MFMA16(al[mt], bh[nt], acc[mt][nt]);
            }
        __syncthreads();
    }

    const long crow0 = mBase + wm * 64;
    const long ccol0 = nBase + wn * 64;
#pragma unroll
    for (int nt = 0; nt < 4; nt++) {
        const long col = ccol0 + nt * 16 + fr;
#pragma unroll
        for (int mt = 0; mt < 4; mt++)
#pragma unroll
            for (int r = 0; r < 4; r++) {
                const long rowg = crow0 + mt * 16 + fq * 4 + r;
                const float v = acc[mt][nt][r];
                const long idx = rowg * (long)N + col;
                const bf16 h = (bf16)v;
                out_hi[idx] = h;
                out_lo[idx] = (bf16)(v - (float)h);
            }
    }
}

// ---------------------------------------------------------------------------
// Flash attention v3: Q-tile 128 rows/block (2 m-tiles/wave), 512 blocks.
// LDS 62.4 KB (Kh/Kl 64x136, Vs 128x72, Ps per-wave 16x72 reused across mt;
// mask read from global) -> 2 blocks/CU. Padded rows -> 2-way aliasing only.
// ---------------------------------------------------------------------------
#define KROW 136
#define VROW 72
#define PROW 72
__global__ __launch_bounds__(256) void flash_attn_k(
    const bf16* __restrict__ qhi, const bf16* __restrict__ qlo,
    const bf16* __restrict__ khi, const bf16* __restrict__ klo,
    const bf16* __restrict__ vt, const float* __restrict__ mask,
    bf16* __restrict__ ctx)
{
    __shared__ __align__(16) bf16 Kh[64 * KROW];
    __shared__ __align__(16) bf16 Kl[64 * KROW];
    __shared__ __align__(16) bf16 Vs[128 * VROW];
    __shared__ __align__(16) bf16 Ps[4][16 * PROW];
    const float scale = 11.3137085f;  // sqrt(128) — faithful *sqrt(d) bug
    const int t = threadIdx.x, w = t >> 6;
    const int fr = t & 15, fq = (t >> 4) & 3;
    const int blk = blockIdx.x;
    const int qt = blk & 15, bh_ = blk >> 4, b = bh_ >> 3, h = bh_ & 7;
    const int qrow0 = qt * 128 + w * 16;   // wave rows: qrow0 + mt*64 + (0..15)

    bf16x8 qh[2][4], ql[2][4];
#pragma unroll
    for (int mt = 0; mt < 2; mt++) {
        const long qoff = ((long)(b * 2048 + qrow0 + mt * 64 + fr)) * 1024 + h * 128 + fq * 8;
#pragma unroll
        for (int s = 0; s < 4; s++) {
            qh[mt][s] = *(const bf16x8*)(qhi + qoff + s * 32);
            ql[mt][s] = *(const bf16x8*)(qlo + qoff + s * 32);
        }
    }
    f32x4 o[2][8];
#pragma unroll
    for (int mt = 0; mt < 2; mt++)
#pragma unroll
        for (int nt = 0; nt < 8; nt++) o[mt][nt] = (f32x4){0.f, 0.f, 0.f, 0.f};
    float m_run[2][4], l_run[2][4];
#pragma unroll
    for (int mt = 0; mt < 2; mt++)
#pragma unroll
        for (int r = 0; r < 4; r++) { m_run[mt][r] = -1e30f; l_run[mt][r] = 0.f; }

    const long kbase = (long)(b * 2048) * 1024 + h * 128 + (long)(t & 15) * 8;
    const long vbase = ((long)bh_ * 128) * 2048 + (long)(t & 7) * 8;
    const float* maskb = mask + b * 2048;

    for (int kt = 0; kt < 32; kt++) {
        __syncthreads();
#pragma unroll
        for (int i = 0; i < 4; i++) {
            const int key = i * 16 + (t >> 4);
            const long g = kbase + (long)(kt * 64 + key) * 1024;
            const bf16x8 vk_h = *(const bf16x8*)(khi + g);
            const bf16x8 vk_l = *(const bf16x8*)(klo + g);
            const int d = i * 32 + (t >> 3);
            const bf16x8 vv = *(const bf16x8*)(vt + vbase + (long)d * 2048 + kt * 64);
            *(bf16x8*)&Kh[key * KROW + (t & 15) * 8] = vk_h;
            *(bf16x8*)&Kl[key * KROW + (t & 15) * 8] = vk_l;
            *(bf16x8*)&Vs[d * VROW + (t & 7) * 8] = vv;
        }
        float madd[4];
#pragma unroll
        for (int ct = 0; ct < 4; ct++)
            madd[ct] = maskb[kt * 64 + ct * 16 + fr] * (-1e9f);
        __syncthreads();

        // QK^T: shared K-fragment reads feed both m-tiles
        f32x4 sc[2][4];
#pragma unroll
        for (int mt = 0; mt < 2; mt++)
#pragma unroll
            for (int ct = 0; ct < 4; ct++) sc[mt][ct] = (f32x4){0.f, 0.f, 0.f, 0.f};
#pragma unroll
        for (int ct = 0; ct < 4; ct++)
#pragma unroll
            for (int s = 0; s < 4; s++) {
                const int off = (ct * 16 + fr) * KROW + s * 32 + fq * 8;
                const bf16x8 kh8 = *(const bf16x8*)&Kh[off];
                const bf16x8 kl8 = *(const bf16x8*)&Kl[off];
#pragma unroll
                for (int mt = 0; mt < 2; mt++) {
                    sc[mt][ct] = MFMA16(qh[mt][s], kh8, sc[mt][ct]);
                    sc[mt][ct] = MFMA16(qh[mt][s], kl8, sc[mt][ct]);
                    sc[mt][ct] = MFMA16(ql[mt][s], kh8, sc[mt][ct]);
                }
            }

        // per m-tile: softmax -> Ps (per-wave, reused) -> rescale o -> PV
#pragma unroll
        for (int mt = 0; mt < 2; mt++) {
            float alpha[4];
#pragma unroll
            for (int r = 0; r < 4; r++) {
                float mx = sc[mt][0][r] * scale + madd[0];
                mx = fmaxf(mx, sc[mt][1][r] * scale + madd[1]);
                mx = fmaxf(mx, sc[mt][2][r] * scale + madd[2]);
                mx = fmaxf(mx, sc[mt][3][r] * scale + madd[3]);
                mx = fmaxf(mx, __shfl_xor(mx, 1));
                mx = fmaxf(mx, __shfl_xor(mx, 2));
                mx = fmaxf(mx, __shfl_xor(mx, 4));
                mx = fmaxf(mx, __shfl_xor(mx, 8));
                const float mn = fmaxf(m_run[mt][r], mx);
                alpha[r] = __expf(m_run[mt][r] - mn);
                m_run[mt][r] = mn;
            }
            float lt[4] = {0.f, 0.f, 0.f, 0.f};
#pragma unroll
            for (int ct = 0; ct < 4; ct++)
#pragma unroll
                for (int r = 0; r < 4; r++) {
                    const float p = __expf(sc[mt][ct][r] * scale + madd[ct] - m_run[mt][r]);
                    lt[r] += p;
                    Ps[w][(fq * 4 + r) * PROW + ct * 16 + fr] = (bf16)p;
                }
#pragma unroll
            for (int r = 0; r < 4; r++) {
                float s_ = lt[r];
                s_ += __shfl_xor(s_, 1); s_ += __shfl_xor(s_, 2);
                s_ += __shfl_xor(s_, 4); s_ += __shfl_xor(s_, 8);
                l_run[mt][r] = l_run[mt][r] * alpha[r] + s_;
            }
#pragma unroll
            for (int nt = 0; nt < 8; nt++)
#pragma unroll
                for (int r = 0; r < 4; r++) o[mt][nt][r] *= alpha[r];

#pragma unroll
            for (int sp = 0; sp < 2; sp++) {
                const bf16x8 pf = *(const bf16x8*)&Ps[w][fr * PROW + sp * 32 + fq * 8];
#pragma unroll
                for (int nt = 0; nt < 8; nt++) {
                    const bf16x8 vf = *(const bf16x8*)&Vs[(nt * 16 + fr) * VROW + sp * 32 + fq * 8];
                    o[mt][nt] = MFMA16(pf, vf, o[mt][nt]);
                }
            }
        }
    }
#pragma unroll
    for (int mt = 0; mt < 2; mt++)
#pragma unroll
        for (int r = 0; r < 4; r++) {
            const float inv = l_run[mt][r] > 0.f ? 1.0f / l_run[mt][r] : 0.f;
#pragma unroll
            for (int nt = 0; nt < 8; nt++) {
                const long idx = ((long)(b * 2048 + qrow0 + mt * 64 + fq * 4 + r)) * 1024
                               + h * 128 + nt * 16 + fr;
                ctx[idx] = (bf16)(o[mt][nt][r] * inv);
            }
        }
}

// ---------------------------------------------------------------------------
// Fused residual + LayerNorm: out = LN(xf + y)*gamma + beta (fp32 out,
// optional bf16 copy out_b for downstream GEMM A-input).
// ---------------------------------------------------------------------------
__global__ __launch_bounds__(256) void add_ln_k(
    const float* __restrict__ xf, const bf16* __restrict__ y,
    const float* __restrict__ gamma, const float* __restrict__ beta,
    float* __restrict__ out, bf16* __restrict__ out_b)
{
    __shared__ float red[8];
    const long row = blockIdx.x;
    const int t = threadIdx.x, lane = t & 63, w = t >> 6;
    float v[4];
    const float4 xv = *(const float4*)(xf + row * 1024 + t * 4);
    v[0] = xv.x; v[1] = xv.y; v[2] = xv.z; v[3] = xv.w;
    const bf16x4 yv = *(const bf16x4*)(y + row * 1024 + t * 4);
    float s = 0.f, s2 = 0.f;
#pragma unroll
    for (int i = 0; i < 4; i++) {
        v[i] += (float)yv[i];
        s += v[i]; s2 += v[i] * v[i];
    }
#pragma unroll
    for (int off = 1; off < 64; off <<= 1) {
        s += __shfl_xor(s, off);
        s2 += __shfl_xor(s2, off);
    }
    if (lane == 0) { red[w] = s; red[4 + w] = s2; }
    __syncthreads();
    s = red[0] + red[1] + red[2] + red[3];
    s2 = red[4] + red[5] + red[6] + red[7];
    const float mean = s * (1.0f / 1024.0f);
    const float var = s2 * (1.0f / 1024.0f) - mean * mean;
    const float rstd = rsqrtf(var + 1e-6f);
    float4 ov;
    ov.x = (v[0] - mean) * rstd * gamma[t * 4 + 0] + beta[t * 4 + 0];
    ov.y = (v[1] - mean) * rstd * gamma[t * 4 + 1] + beta[t * 4 + 1];
    ov.z = (v[2] - mean) * rstd * gamma[t * 4 + 2] + beta[t * 4 + 2];
    ov.w = (v[3] - mean) * rstd * gamma[t * 4 + 3] + beta[t * 4 + 3];
    *(float4*)(out + row * 1024 + t * 4) = ov;
    if (out_b) {
        bf16x4 hb;
        hb[0] = (bf16)ov.x; hb[1] = (bf16)ov.y; hb[2] = (bf16)ov.z; hb[3] = (bf16)ov.w;
        *(bf16x4*)(out_b + row * 1024 + t * 4) = hb;
    }
}

// ===========================================================================
extern "C" void kernel_launch(void* const* d_in, const int* in_sizes, int n_in,
                              void* d_out, int out_size, void* d_ws, size_t ws_size,
                              hipStream_t stream)
{
    (void)in_sizes; (void)n_in; (void)out_size; (void)ws_size;
    const float* x     = (const float*)d_in[0];
    const float* mask  = (const float*)d_in[1];
    const float* Wq    = (const float*)d_in[2];
    const float* Wk    = (const float*)d_in[3];
    const float* Wv    = (const float*)d_in[4];
    const float* Wo    = (const float*)d_in[5];
    const float* W1    = (const float*)d_in[6];
    const float* b1    = (const float*)d_in[7];
    const float* W2    = (const float*)d_in[8];
    const float* b2    = (const float*)d_in[9];
    const float* gamma = (const float*)d_in[10];
    const float* beta  = (const float*)d_in[11];
    float* out = (float*)d_out;   // fp32 output per reference dtype

    char* ws = (char*)d_ws;
    const size_t SZ = 8192ul * 1024 * 2;           // 16 MiB per [8192,1024] bf16
    bf16* qhi  = (bf16*)(ws + 0 * SZ);
    bf16* qlo  = (bf16*)(ws + 1 * SZ);
    bf16* khi  = (bf16*)(ws + 2 * SZ);
    bf16* klo  = (bf16*)(ws + 3 * SZ);
    bf16* hbuf = (bf16*)(ws + 0 * SZ);             // [8192,4096] aliases q/k (dead post-attn)
    bf16* vbuf = (bf16*)(ws + 4 * SZ);
    bf16* ctxb = vbuf;                             // aliases v (dead after vt built)
    bf16* vtb  = (bf16*)(ws + 5 * SZ);
    bf16* fbuf = vtb;                              // aliases vt (dead post-attn)
    bf16* xh   = (bf16*)(ws + 6 * SZ);
    bf16* xl   = (bf16*)(ws + 7 * SZ);
    bf16* aob  = xl;                               // aliases xl (dead after Q/K proj)
    float* x1f = (float*)(ws + 8 * SZ);            // fp32 x1 [8192,1024] = 32 MiB
    bf16* x1b  = (bf16*)(ws + 10 * SZ);
    char* wts  = ws + 11 * SZ;
    bf16* Wqth = (bf16*)(wts);
    bf16* Wqtl = (bf16*)(wts + 1 * 2097152);
    bf16* Wkth = (bf16*)(wts + 2 * 2097152);
    bf16* Wktl = (bf16*)(wts + 3 * 2097152);
    bf16* Wvt  = (bf16*)(wts + 4 * 2097152);
    bf16* Wot  = (bf16*)(wts + 5 * 2097152);
    bf16* W1t  = (bf16*)(wts + 6 * 2097152);
    bf16* W2t  = (bf16*)(wts + 6 * 2097152 + 8388608);

    const dim3 blk(256);
    split_f32_k<<<dim3(8192), blk, 0, stream>>>(x, xh, xl);
    // weight transposes -> [N][K] bf16, LDS-tiled
    transpose_f32_k<<<dim3(16, 16), blk, 0, stream>>>(Wq, Wqth, Wqtl, 1024, 1024);
    transpose_f32_k<<<dim3(16, 16), blk, 0, stream>>>(Wk, Wkth, Wktl, 1024, 1024);
    transpose_f32_k<<<dim3(16, 16), blk, 0, stream>>>(Wv, Wvt, nullptr, 1024, 1024);
    transpose_f32_k<<<dim3(16, 16), blk, 0, stream>>>(Wo, Wot, nullptr, 1024, 1024);
    transpose_f32_k<<<dim3(64, 16), blk, 0, stream>>>(W1, W1t, nullptr, 4096, 1024);
    transpose_f32_k<<<dim3(16, 64), blk, 0, stream>>>(W2, W2t, nullptr, 1024, 4096);
    // Q/K projections split-precision; V plain bf16
    gemm_split_k<<<dim3(8, 64), blk, 0, stream>>>(xh, xl, Wqth, Wqtl, qhi, qlo, 8192, 1024, 1024);
    gemm_split_k<<<dim3(8, 64), blk, 0, stream>>>(xh, xl, Wkth, Wktl, khi, klo, 8192, 1024, 1024);
    gemm_bf16_k<<<dim3(8, 64), blk, 0, stream>>>(xh, Wvt, vbuf, nullptr, 0, 8192, 1024, 1024);
    // per-head V transpose: [b*2048+s][h*128+d] -> [bh][d][s]
    transpose_bf16_k<<<dim3(2, 32, 32), blk, 0, stream>>>(vbuf, vtb, 1024, 2048, 8,
                                                          (long)2048 * 1024, 128L, (long)128 * 2048);
    flash_attn_k<<<dim3(512), blk, 0, stream>>>(qhi, qlo, khi, klo, vtb, mask, ctxb);
    gemm_bf16_k<<<dim3(8, 64), blk, 0, stream>>>(ctxb, Wot, aob, nullptr, 0, 8192, 1024, 1024);
    // x1 = LN(x + attn_out): fp32 master + fused bf16 copy
    add_ln_k<<<dim3(8192), blk, 0, stream>>>(x, aob, gamma, beta, x1f, x1b);
    gemm_bf16_k<<<dim3(32, 64), blk, 0, stream>>>(x1b, W1t, hbuf, b1, 1, 8192, 4096, 1024);
    gemm_bf16_k<<<dim3(8, 64), blk, 0, stream>>>(hbuf, W2t, fbuf, b2, 0, 8192, 1024, 4096);
    add_ln_k<<<dim3(8192), blk, 0, stream>>>(x1f, fbuf, gamma, beta, out, nullptr);
}

// Round 8
// 750.637 us; speedup vs baseline: 1.4627x; 1.0778x over previous
//
#include <hip/hip_runtime.h>

// ============================================================================
// EncoderLayer: x -> MHA(+residual,LN) -> FFN(+residual,LN)
// B=4 S=2048 H=1024 F=4096 nh=8 d=128. Inputs fp32, OUTPUT fp32.
// Core compute bf16 MFMA; Q/K path split hi/lo bf16 (faithful *sqrt(d) bug).
// R8: flash __launch_bounds__(256,2). R7 counters: VGPR 184 + ~96 acc = 280
//     > 256 -> 1 wave/SIMD (Occ 11.5%) despite LDS fitting 2 blocks/CU.
//     Cap combined regs at 256 to restore 2 waves/SIMD overlap.
// ============================================================================

typedef __bf16 bf16;
typedef __bf16 bf16x4 __attribute__((ext_vector_type(4)));
typedef __bf16 bf16x8 __attribute__((ext_vector_type(8)));
typedef float  f32x4  __attribute__((ext_vector_type(4)));

#define MFMA16(a, b, c) __builtin_amdgcn_mfma_f32_16x16x32_bf16(a, b, c, 0, 0, 0)

typedef const __attribute__((address_space(1))) void* gas_cptr;
typedef __attribute__((address_space(3))) void* las_ptr;

__device__ __forceinline__ void g2l16(const void* g, void* l) {
    __builtin_amdgcn_global_load_lds((gas_cptr)g, (las_ptr)l, 16, 0, 0);
}

__device__ __forceinline__ uint b16bits(bf16 v) {
    union { bf16 h; unsigned short u; } cv; cv.h = v; return (uint)cv.u;
}

// ---------------------------------------------------------------------------
// x (fp32) -> hi/lo bf16 split. One float4 per thread.
// ---------------------------------------------------------------------------
__global__ __launch_bounds__(256) void split_f32_k(
    const float* __restrict__ in, bf16* __restrict__ hi, bf16* __restrict__ lo)
{
    const long i = (long)blockIdx.x * 256 + threadIdx.x;
    const float4 v = *(const float4*)(in + i * 4);
    const float a[4] = {v.x, v.y, v.z, v.w};
    bf16x4 h, l;
#pragma unroll
    for (int j = 0; j < 4; j++) {
        h[j] = (bf16)a[j];
        l[j] = (bf16)(a[j] - (float)h[j]);
    }
    *(bf16x4*)(hi + i * 4) = h;
    *(bf16x4*)(lo + i * 4) = l;
}

// ---------------------------------------------------------------------------
// fp32 [R][C] -> bf16 [C][R] transpose (hi + optional lo residual).
// 64x64 tiles, u32 row-pair packing in LDS (conflict-free).
// ---------------------------------------------------------------------------
__global__ __launch_bounds__(256) void transpose_f32_k(
    const float* __restrict__ in, bf16* __restrict__ out_hi, bf16* __restrict__ out_lo,
    int in_rs, int out_rs)
{
    __shared__ uint Th[64][33];
    __shared__ uint Tl[64][33];
    const long c0 = (long)blockIdx.x * 64;
    const long r0 = (long)blockIdx.y * 64;
    const int t = threadIdx.x, rp = t >> 3, cc = t & 7;
    const float* pa = in + (r0 + 2 * rp) * (long)in_rs + c0 + cc * 8;
    const float* pb = pa + in_rs;
    float a[8], b[8];
    *(float4*)&a[0] = *(const float4*)pa;
    *(float4*)&a[4] = *(const float4*)(pa + 4);
    *(float4*)&b[0] = *(const float4*)pb;
    *(float4*)&b[4] = *(const float4*)(pb + 4);
#pragma unroll
    for (int j = 0; j < 8; j++) {
        const bf16 ah = (bf16)a[j], bh = (bf16)b[j];
        Th[cc * 8 + j][rp] = b16bits(ah) | (b16bits(bh) << 16);
        const bf16 al = (bf16)(a[j] - (float)ah), bl = (bf16)(b[j] - (float)bh);
        Tl[cc * 8 + j][rp] = b16bits(al) | (b16bits(bl) << 16);
    }
    __syncthreads();
#pragma unroll
    for (int i = 0; i < 2; i++) {
        const int task = i * 256 + t;
        const int c = task >> 3, ch = task & 7;
        uint4 wv;
        wv.x = Th[c][ch * 4 + 0]; wv.y = Th[c][ch * 4 + 1];
        wv.z = Th[c][ch * 4 + 2]; wv.w = Th[c][ch * 4 + 3];
        *(uint4*)(out_hi + (c0 + c) * (long)out_rs + r0 + ch * 8) = wv;
        if (out_lo) {
            uint4 wl;
            wl.x = Tl[c][ch * 4 + 0]; wl.y = Tl[c][ch * 4 + 1];
            wl.z = Tl[c][ch * 4 + 2]; wl.w = Tl[c][ch * 4 + 3];
            *(uint4*)(out_lo + (c0 + c) * (long)out_rs + r0 + ch * 8) = wl;
        }
    }
}

// ---------------------------------------------------------------------------
// bf16 [R][C] -> bf16 [C][R] transpose (per-head V).
// batch z: in_off = (z/nh)*bo_in + (z%nh)*bi_in ; out_off = z*bo_out
// ---------------------------------------------------------------------------
__global__ __launch_bounds__(256) void transpose_bf16_k(
    const bf16* __restrict__ in, bf16* __restrict__ out,
    int in_rs, int out_rs, int nh, long bo_in, long bi_in, long bo_out)
{
    __shared__ uint T[64][33];
    const int z = blockIdx.z;
    const bf16* inp = in + (long)(z / nh) * bo_in + (long)(z % nh) * bi_in;
    bf16* outp = out + (long)z * bo_out;
    const long c0 = (long)blockIdx.x * 64;
    const long r0 = (long)blockIdx.y * 64;
    const int t = threadIdx.x, rp = t >> 3, cc = t & 7;

    const uint4 ra = *(const uint4*)(inp + (r0 + 2 * rp) * (long)in_rs + c0 + cc * 8);
    const uint4 rb = *(const uint4*)(inp + (r0 + 2 * rp + 1) * (long)in_rs + c0 + cc * 8);
    const uint a32[4] = {ra.x, ra.y, ra.z, ra.w};
    const uint b32[4] = {rb.x, rb.y, rb.z, rb.w};
#pragma unroll
    for (int j = 0; j < 8; j++) {
        const uint av = (j & 1) ? (a32[j >> 1] >> 16) : (a32[j >> 1] & 0xffffu);
        const uint bv = (j & 1) ? (b32[j >> 1] >> 16) : (b32[j >> 1] & 0xffffu);
        T[cc * 8 + j][rp] = av | (bv << 16);
    }
    __syncthreads();
#pragma unroll
    for (int i = 0; i < 2; i++) {
        const int task = i * 256 + t;
        const int c = task >> 3, ch = task & 7;
        uint4 wv;
        wv.x = T[c][ch * 4 + 0]; wv.y = T[c][ch * 4 + 1];
        wv.z = T[c][ch * 4 + 2]; wv.w = T[c][ch * 4 + 3];
        *(uint4*)(outp + (c0 + c) * (long)out_rs + r0 + ch * 8) = wv;
    }
}

// ---------------------------------------------------------------------------
// GEMM: C[M,N] = A[M,K] @ Bt[N,K]^T  (bf16, fp32 acc). m97 recipe.
// ---------------------------------------------------------------------------
__global__ __launch_bounds__(256) void gemm_bf16_k(
    const bf16* __restrict__ A, const bf16* __restrict__ Bt,
    bf16* __restrict__ out,
    const float* __restrict__ bias, int relu, int M, int N, int K)
{
    __shared__ __align__(16) bf16 As[128 * 32];
    __shared__ __align__(16) bf16 Bs[128 * 32];
    const int t = threadIdx.x;
    const int fr = t & 15, fq = (t >> 4) & 3;
    const int w = t >> 6, wm = w & 1, wn = w >> 1;
    const long mBase = (long)blockIdx.y * 128;
    const long nBase = (long)blockIdx.x * 128;

    f32x4 acc[4][4];
#pragma unroll
    for (int i = 0; i < 4; i++)
#pragma unroll
        for (int j = 0; j < 4; j++) acc[i][j] = (f32x4){0.f, 0.f, 0.f, 0.f};

    const int arow = t >> 2;
    const int akc  = (t & 3) * 8;
    const bf16* ga0 = A + (mBase + arow) * (long)K + akc;
    const bf16* ga1 = A + (mBase + arow + 64) * (long)K + akc;
    const bf16* gb0 = Bt + (nBase + arow) * (long)K + akc;
    const bf16* gb1 = Bt + (nBase + arow + 64) * (long)K + akc;
    bf16* la0 = &As[t * 8];
    bf16* la1 = &As[(256 + t) * 8];
    bf16* lb0 = &Bs[t * 8];
    bf16* lb1 = &Bs[(256 + t) * 8];

    const int aoff = (wm * 64 + fr) * 32 + fq * 8;
    const int boff = (wn * 64 + fr) * 32 + fq * 8;

    for (int kt = 0; kt < K; kt += 32) {
        g2l16(ga0 + kt, la0);
        g2l16(ga1 + kt, la1);
        g2l16(gb0 + kt, lb0);
        g2l16(gb1 + kt, lb1);
        __syncthreads();
        bf16x8 af[4], bfv[4];
#pragma unroll
        for (int mt = 0; mt < 4; mt++) af[mt] = *(const bf16x8*)&As[aoff + mt * 512];
#pragma unroll
        for (int nt = 0; nt < 4; nt++) bfv[nt] = *(const bf16x8*)&Bs[boff + nt * 512];
#pragma unroll
        for (int mt = 0; mt < 4; mt++)
#pragma unroll
            for (int nt = 0; nt < 4; nt++)
                acc[mt][nt] = MFMA16(af[mt], bfv[nt], acc[mt][nt]);
        __syncthreads();
    }

    const long crow0 = mBase + wm * 64;
    const long ccol0 = nBase + wn * 64;
#pragma unroll
    for (int nt = 0; nt < 4; nt++) {
        const long col = ccol0 + nt * 16 + fr;
        const float bv = bias ? bias[col] : 0.0f;
#pragma unroll
        for (int mt = 0; mt < 4; mt++)
#pragma unroll
            for (int r = 0; r < 4; r++) {
                const long rowg = crow0 + mt * 16 + fq * 4 + r;
                float v = acc[mt][nt][r] + bv;
                if (relu) v = fmaxf(v, 0.0f);
                out[rowg * (long)N + col] = (bf16)v;
            }
    }
}

// ---------------------------------------------------------------------------
// Split-precision GEMM (Q/K): C = Ah@Bh^T + Ah@Bl^T + Al@Bh^T, split out.
// ---------------------------------------------------------------------------
__global__ __launch_bounds__(256) void gemm_split_k(
    const bf16* __restrict__ Ah, const bf16* __restrict__ Al,
    const bf16* __restrict__ Bh, const bf16* __restrict__ Bl,
    bf16* __restrict__ out_hi, bf16* __restrict__ out_lo, int M, int N, int K)
{
    __shared__ __align__(16) bf16 Ahs[128 * 32];
    __shared__ __align__(16) bf16 Als[128 * 32];
    __shared__ __align__(16) bf16 Bhs[128 * 32];
    __shared__ __align__(16) bf16 Bls[128 * 32];
    const int t = threadIdx.x;
    const int fr = t & 15, fq = (t >> 4) & 3;
    const int w = t >> 6, wm = w & 1, wn = w >> 1;
    const long mBase = (long)blockIdx.y * 128;
    const long nBase = (long)blockIdx.x * 128;

    f32x4 acc[4][4];
#pragma unroll
    for (int i = 0; i < 4; i++)
#pragma unroll
        for (int j = 0; j < 4; j++) acc[i][j] = (f32x4){0.f, 0.f, 0.f, 0.f};

    const int arow = t >> 2;
    const int akc  = (t & 3) * 8;
    const long ga0 = (mBase + arow) * (long)K + akc;
    const long ga1 = (mBase + arow + 64) * (long)K + akc;
    const long gb0 = (nBase + arow) * (long)K + akc;
    const long gb1 = (nBase + arow + 64) * (long)K + akc;

    const int aoff = (wm * 64 + fr) * 32 + fq * 8;
    const int boff = (wn * 64 + fr) * 32 + fq * 8;

    for (int kt = 0; kt < K; kt += 32) {
        g2l16(Ah + ga0 + kt, &Ahs[t * 8]);
        g2l16(Ah + ga1 + kt, &Ahs[(256 + t) * 8]);
        g2l16(Al + ga0 + kt, &Als[t * 8]);
        g2l16(Al + ga1 + kt, &Als[(256 + t) * 8]);
        g2l16(Bh + gb0 + kt, &Bhs[t * 8]);
        g2l16(Bh + gb1 + kt, &Bhs[(256 + t) * 8]);
        g2l16(Bl + gb0 + kt, &Bls[t * 8]);
        g2l16(Bl + gb1 + kt, &Bls[(256 + t) * 8]);
        __syncthreads();
        bf16x8 ah[4], al[4], bh[4], bl[4];
#pragma unroll
        for (int mt = 0; mt < 4; mt++) {
            ah[mt] = *(const bf16x8*)&Ahs[aoff + mt * 512];
            al[mt] = *(const bf16x8*)&Als[aoff + mt * 512];
        }
#pragma unroll
        for (int nt = 0; nt < 4; nt++) {
            bh[nt] = *(const bf16x8*)&Bhs[boff + nt * 512];
            bl[nt] = *(const bf16x8*)&Bls[boff + nt * 512];
        }
#pragma unroll
        for (int mt = 0; mt < 4; mt++)
#pragma unroll
            for (int nt = 0; nt < 4; nt++) {
                acc[mt][nt] = MFMA16(ah[mt], bh[nt], acc[mt][nt]);
                acc[mt][nt] = MFMA16(ah[mt], bl[nt], acc[mt][nt]);
                acc[mt][nt] = MFMA16(al[mt], bh[nt], acc[mt][nt]);
            }
        __syncthreads();
    }

    const long crow0 = mBase + wm * 64;
    const long ccol0 = nBase + wn * 64;
#pragma unroll
    for (int nt = 0; nt < 4; nt++) {
        const long col = ccol0 + nt * 16 + fr;
#pragma unroll
        for (int mt = 0; mt < 4; mt++)
#pragma unroll
            for (int r = 0; r < 4; r++) {
                const long rowg = crow0 + mt * 16 + fq * 4 + r;
                const float v = acc[mt][nt][r];
                const long idx = rowg * (long)N + col;
                const bf16 h = (bf16)v;
                out_hi[idx] = h;
                out_lo[idx] = (bf16)(v - (float)h);
            }
    }
}

// ---------------------------------------------------------------------------
// Flash attention v4: Q-tile 128 rows/block (2 m-tiles/wave), 512 blocks.
// LDS 62.4 KB; __launch_bounds__(256,2) caps combined VGPR+AGPR at 256 so
// 2 waves/SIMD co-reside (R7: 184+96=280 -> 1 wave/SIMD, Occ 11.5%).
// ---------------------------------------------------------------------------
#define KROW 136
#define VROW 72
#define PROW 72
__global__ __launch_bounds__(256, 2) void flash_attn_k(
    const bf16* __restrict__ qhi, const bf16* __restrict__ qlo,
    const bf16* __restrict__ khi, const bf16* __restrict__ klo,
    const bf16* __restrict__ vt, const float* __restrict__ mask,
    bf16* __restrict__ ctx)
{
    __shared__ __align__(16) bf16 Kh[64 * KROW];
    __shared__ __align__(16) bf16 Kl[64 * KROW];
    __shared__ __align__(16) bf16 Vs[128 * VROW];
    __shared__ __align__(16) bf16 Ps[4][16 * PROW];
    const float scale = 11.3137085f;  // sqrt(128) — faithful *sqrt(d) bug
    const int t = threadIdx.x, w = t >> 6;
    const int fr = t & 15, fq = (t >> 4) & 3;
    const int blk = blockIdx.x;
    const int qt = blk & 15, bh_ = blk >> 4, b = bh_ >> 3, h = bh_ & 7;
    const int qrow0 = qt * 128 + w * 16;   // wave rows: qrow0 + mt*64 + (0..15)

    bf16x8 qh[2][4], ql[2][4];
#pragma unroll
    for (int mt = 0; mt < 2; mt++) {
        const long qoff = ((long)(b * 2048 + qrow0 + mt * 64 + fr)) * 1024 + h * 128 + fq * 8;
#pragma unroll
        for (int s = 0; s < 4; s++) {
            qh[mt][s] = *(const bf16x8*)(qhi + qoff + s * 32);
            ql[mt][s] = *(const bf16x8*)(qlo + qoff + s * 32);
        }
    }
    f32x4 o[2][8];
#pragma unroll
    for (int mt = 0; mt < 2; mt++)
#pragma unroll
        for (int nt = 0; nt < 8; nt++) o[mt][nt] = (f32x4){0.f, 0.f, 0.f, 0.f};
    float m_run[2][4], l_run[2][4];
#pragma unroll
    for (int mt = 0; mt < 2; mt++)
#pragma unroll
        for (int r = 0; r < 4; r++) { m_run[mt][r] = -1e30f; l_run[mt][r] = 0.f; }

    const long kbase = (long)(b * 2048) * 1024 + h * 128 + (long)(t & 15) * 8;
    const long vbase = ((long)bh_ * 128) * 2048 + (long)(t & 7) * 8;
    const float* maskb = mask + b * 2048;

    for (int kt = 0; kt < 32; kt++) {
        __syncthreads();
#pragma unroll
        for (int i = 0; i < 4; i++) {
            const int key = i * 16 + (t >> 4);
            const long g = kbase + (long)(kt * 64 + key) * 1024;
            const bf16x8 vk_h = *(const bf16x8*)(khi + g);
            const bf16x8 vk_l = *(const bf16x8*)(klo + g);
            const int d = i * 32 + (t >> 3);
            const bf16x8 vv = *(const bf16x8*)(vt + vbase + (long)d * 2048 + kt * 64);
            *(bf16x8*)&Kh[key * KROW + (t & 15) * 8] = vk_h;
            *(bf16x8*)&Kl[key * KROW + (t & 15) * 8] = vk_l;
            *(bf16x8*)&Vs[d * VROW + (t & 7) * 8] = vv;
        }
        float madd[4];
#pragma unroll
        for (int ct = 0; ct < 4; ct++)
            madd[ct] = maskb[kt * 64 + ct * 16 + fr] * (-1e9f);
        __syncthreads();

        // QK^T: shared K-fragment reads feed both m-tiles
        f32x4 sc[2][4];
#pragma unroll
        for (int mt = 0; mt < 2; mt++)
#pragma unroll
            for (int ct = 0; ct < 4; ct++) sc[mt][ct] = (f32x4){0.f, 0.f, 0.f, 0.f};
#pragma unroll
        for (int ct = 0; ct < 4; ct++)
#pragma unroll
            for (int s = 0; s < 4; s++) {
                const int off = (ct * 16 + fr) * KROW + s * 32 + fq * 8;
                const bf16x8 kh8 = *(const bf16x8*)&Kh[off];
                const bf16x8 kl8 = *(const bf16x8*)&Kl[off];
#pragma unroll
                for (int mt = 0; mt < 2; mt++) {
                    sc[mt][ct] = MFMA16(qh[mt][s], kh8, sc[mt][ct]);
                    sc[mt][ct] = MFMA16(qh[mt][s], kl8, sc[mt][ct]);
                    sc[mt][ct] = MFMA16(ql[mt][s], kh8, sc[mt][ct]);
                }
            }

        // per m-tile: softmax -> Ps (per-wave, reused) -> rescale o -> PV
#pragma unroll
        for (int mt = 0; mt < 2; mt++) {
            float alpha[4];
#pragma unroll
            for (int r = 0; r < 4; r++) {
                float mx = sc[mt][0][r] * scale + madd[0];
                mx = fmaxf(mx, sc[mt][1][r] * scale + madd[1]);
                mx = fmaxf(mx, sc[mt][2][r] * scale + madd[2]);
                mx = fmaxf(mx, sc[mt][3][r] * scale + madd[3]);
                mx = fmaxf(mx, __shfl_xor(mx, 1));
                mx = fmaxf(mx, __shfl_xor(mx, 2));
                mx = fmaxf(mx, __shfl_xor(mx, 4));
                mx = fmaxf(mx, __shfl_xor(mx, 8));
                const float mn = fmaxf(m_run[mt][r], mx);
                alpha[r] = __expf(m_run[mt][r] - mn);
                m_run[mt][r] = mn;
            }
            float lt[4] = {0.f, 0.f, 0.f, 0.f};
#pragma unroll
            for (int ct = 0; ct < 4; ct++)
#pragma unroll
                for (int r = 0; r < 4; r++) {
                    const float p = __expf(sc[mt][ct][r] * scale + madd[ct] - m_run[mt][r]);
                    lt[r] += p;
                    Ps[w][(fq * 4 + r) * PROW + ct * 16 + fr] = (bf16)p;
                }
#pragma unroll
            for (int r = 0; r < 4; r++) {
                float s_ = lt[r];
                s_ += __shfl_xor(s_, 1); s_ += __shfl_xor(s_, 2);
                s_ += __shfl_xor(s_, 4); s_ += __shfl_xor(s_, 8);
                l_run[mt][r] = l_run[mt][r] * alpha[r] + s_;
            }
#pragma unroll
            for (int nt = 0; nt < 8; nt++)
#pragma unroll
                for (int r = 0; r < 4; r++) o[mt][nt][r] *= alpha[r];

#pragma unroll
            for (int sp = 0; sp < 2; sp++) {
                const bf16x8 pf = *(const bf16x8*)&Ps[w][fr * PROW + sp * 32 + fq * 8];
#pragma unroll
                for (int nt = 0; nt < 8; nt++) {
                    const bf16x8 vf = *(const bf16x8*)&Vs[(nt * 16 + fr) * VROW + sp * 32 + fq * 8];
                    o[mt][nt] = MFMA16(pf, vf, o[mt][nt]);
                }
            }
        }
    }
#pragma unroll
    for (int mt = 0; mt < 2; mt++)
#pragma unroll
        for (int r = 0; r < 4; r++) {
            const float inv = l_run[mt][r] > 0.f ? 1.0f / l_run[mt][r] : 0.f;
#pragma unroll
            for (int nt = 0; nt < 8; nt++) {
                const long idx = ((long)(b * 2048 + qrow0 + mt * 64 + fq * 4 + r)) * 1024
                               + h * 128 + nt * 16 + fr;
                ctx[idx] = (bf16)(o[mt][nt][r] * inv);
            }
        }
}

// ---------------------------------------------------------------------------
// Fused residual + LayerNorm: out = LN(xf + y)*gamma + beta (fp32 out,
// optional bf16 copy out_b for downstream GEMM A-input).
// ---------------------------------------------------------------------------
__global__ __launch_bounds__(256) void add_ln_k(
    const float* __restrict__ xf, const bf16* __restrict__ y,
    const float* __restrict__ gamma, const float* __restrict__ beta,
    float* __restrict__ out, bf16* __restrict__ out_b)
{
    __shared__ float red[8];
    const long row = blockIdx.x;
    const int t = threadIdx.x, lane = t & 63, w = t >> 6;
    float v[4];
    const float4 xv = *(const float4*)(xf + row * 1024 + t * 4);
    v[0] = xv.x; v[1] = xv.y; v[2] = xv.z; v[3] = xv.w;
    const bf16x4 yv = *(const bf16x4*)(y + row * 1024 + t * 4);
    float s = 0.f, s2 = 0.f;
#pragma unroll
    for (int i = 0; i < 4; i++) {
        v[i] += (float)yv[i];
        s += v[i]; s2 += v[i] * v[i];
    }
#pragma unroll
    for (int off = 1; off < 64; off <<= 1) {
        s += __shfl_xor(s, off);
        s2 += __shfl_xor(s2, off);
    }
    if (lane == 0) { red[w] = s; red[4 + w] = s2; }
    __syncthreads();
    s = red[0] + red[1] + red[2] + red[3];
    s2 = red[4] + red[5] + red[6] + red[7];
    const float mean = s * (1.0f / 1024.0f);
    const float var = s2 * (1.0f / 1024.0f) - mean * mean;
    const float rstd = rsqrtf(var + 1e-6f);
    float4 ov;
    ov.x = (v[0] - mean) * rstd * gamma[t * 4 + 0] + beta[t * 4 + 0];
    ov.y = (v[1] - mean) * rstd * gamma[t * 4 + 1] + beta[t * 4 + 1];
    ov.z = (v[2] - mean) * rstd * gamma[t * 4 + 2] + beta[t * 4 + 2];
    ov.w = (v[3] - mean) * rstd * gamma[t * 4 + 3] + beta[t * 4 + 3];
    *(float4*)(out + row * 1024 + t * 4) = ov;
    if (out_b) {
        bf16x4 hb;
        hb[0] = (bf16)ov.x; hb[1] = (bf16)ov.y; hb[2] = (bf16)ov.z; hb[3] = (bf16)ov.w;
        *(bf16x4*)(out_b + row * 1024 + t * 4) = hb;
    }
}

// ===========================================================================
extern "C" void kernel_launch(void* const* d_in, const int* in_sizes, int n_in,
                              void* d_out, int out_size, void* d_ws, size_t ws_size,
                              hipStream_t stream)
{
    (void)in_sizes; (void)n_in; (void)out_size; (void)ws_size;
    const float* x     = (const float*)d_in[0];
    const float* mask  = (const float*)d_in[1];
    const float* Wq    = (const float*)d_in[2];
    const float* Wk    = (const float*)d_in[3];
    const float* Wv    = (const float*)d_in[4];
    const float* Wo    = (const float*)d_in[5];
    const float* W1    = (const float*)d_in[6];
    const float* b1    = (const float*)d_in[7];
    const float* W2    = (const float*)d_in[8];
    const float* b2    = (const float*)d_in[9];
    const float* gamma = (const float*)d_in[10];
    const float* beta  = (const float*)d_in[11];
    float* out = (float*)d_out;   // fp32 output per reference dtype

    char* ws = (char*)d_ws;
    const size_t SZ = 8192ul * 1024 * 2;           // 16 MiB per [8192,1024] bf16
    bf16* qhi  = (bf16*)(ws + 0 * SZ);
    bf16* qlo  = (bf16*)(ws + 1 * SZ);
    bf16* khi  = (bf16*)(ws + 2 * SZ);
    bf16* klo  = (bf16*)(ws + 3 * SZ);
    bf16* hbuf = (bf16*)(ws + 0 * SZ);             // [8192,4096] aliases q/k (dead post-attn)
    bf16* vbuf = (bf16*)(ws + 4 * SZ);
    bf16* ctxb = vbuf;                             // aliases v (dead after vt built)
    bf16* vtb  = (bf16*)(ws + 5 * SZ);
    bf16* fbuf = vtb;                              // aliases vt (dead post-attn)
    bf16* xh   = (bf16*)(ws + 6 * SZ);
    bf16* xl   = (bf16*)(ws + 7 * SZ);
    bf16* aob  = xl;                               // aliases xl (dead after Q/K proj)
    float* x1f = (float*)(ws + 8 * SZ);            // fp32 x1 [8192,1024] = 32 MiB
    bf16* x1b  = (bf16*)(ws + 10 * SZ);
    char* wts  = ws + 11 * SZ;
    bf16* Wqth = (bf16*)(wts);
    bf16* Wqtl = (bf16*)(wts + 1 * 2097152);
    bf16* Wkth = (bf16*)(wts + 2 * 2097152);
    bf16* Wktl = (bf16*)(wts + 3 * 2097152);
    bf16* Wvt  = (bf16*)(wts + 4 * 2097152);
    bf16* Wot  = (bf16*)(wts + 5 * 2097152);
    bf16* W1t  = (bf16*)(wts + 6 * 2097152);
    bf16* W2t  = (bf16*)(wts + 6 * 2097152 + 8388608);

    const dim3 blk(256);
    split_f32_k<<<dim3(8192), blk, 0, stream>>>(x, xh, xl);
    // weight transposes -> [N][K] bf16, LDS-tiled
    transpose_f32_k<<<dim3(16, 16), blk, 0, stream>>>(Wq, Wqth, Wqtl, 1024, 1024);
    transpose_f32_k<<<dim3(16, 16), blk, 0, stream>>>(Wk, Wkth, Wktl, 1024, 1024);
    transpose_f32_k<<<dim3(16, 16), blk, 0, stream>>>(Wv, Wvt, nullptr, 1024, 1024);
    transpose_f32_k<<<dim3(16, 16), blk, 0, stream>>>(Wo, Wot, nullptr, 1024, 1024);
    transpose_f32_k<<<dim3(64, 16), blk, 0, stream>>>(W1, W1t, nullptr, 4096, 1024);
    transpose_f32_k<<<dim3(16, 64), blk, 0, stream>>>(W2, W2t, nullptr, 1024, 4096);
    // Q/K projections split-precision; V plain bf16
    gemm_split_k<<<dim3(8, 64), blk, 0, stream>>>(xh, xl, Wqth, Wqtl, qhi, qlo, 8192, 1024, 1024);
    gemm_split_k<<<dim3(8, 64), blk, 0, stream>>>(xh, xl, Wkth, Wktl, khi, klo, 8192, 1024, 1024);
    gemm_bf16_k<<<dim3(8, 64), blk, 0, stream>>>(xh, Wvt, vbuf, nullptr, 0, 8192, 1024, 1024);
    // per-head V transpose: [b*2048+s][h*128+d] -> [bh][d][s]
    transpose_bf16_k<<<dim3(2, 32, 32), blk, 0, stream>>>(vbuf, vtb, 1024, 2048, 8,
                                                          (long)2048 * 1024, 128L, (long)128 * 2048);
    flash_attn_k<<<dim3(512), blk, 0, stream>>>(qhi, qlo, khi, klo, vtb, mask, ctxb);
    gemm_bf16_k<<<dim3(8, 64), blk, 0, stream>>>(ctxb, Wot, aob, nullptr, 0, 8192, 1024, 1024);
    // x1 = LN(x + attn_out): fp32 master + fused bf16 copy
    add_ln_k<<<dim3(8192), blk, 0, stream>>>(x, aob, gamma, beta, x1f, x1b);
    gemm_bf16_k<<<dim3(32, 64), blk, 0, stream>>>(x1b, W1t, hbuf, b1, 1, 8192, 4096, 1024);
    gemm_bf16_k<<<dim3(8, 64), blk, 0, stream>>>(hbuf, W2t, fbuf, b2, 0, 8192, 1024, 4096);
    add_ln_k<<<dim3(8192), blk, 0, stream>>>(x1f, fbuf, gamma, beta, out, nullptr);
}